// Round 2
// baseline (14554.713 us; speedup 1.0000x reference)
//
#include <hip/hip_runtime.h>
#include <cstdint>

// binary_disordered_RNNwavefunction: 128-step 2-layer GRU + MLP + softmax +
// threefry categorical sampling, B=8192, H=128, I=2.
//
// R2 changes vs R1:
//  - BT 16 -> 8, grid 1024, __launch_bounds__(256,4): 4 blocks/CU = 16 waves/CU
//    (R1 measured OccupancyPercent 20.7 with 8 waves/CU).
//  - Conflict-free batch-row ownership: thread owns rows {tq, tq+4} (tq=tid&3)
//    so one ds_read_b128's 4 distinct addresses land on 4 disjoint 4-bank
//    spans (banks 4*tq + 16*i + k). R1 owned rows {4t..4t+3}+i -> 2 addresses
//    per bank group -> SQ_LDS_BANK_CONFLICT 8.85e8.
//
// RNG (verified passing in R1): modern JAX (threefry_partitionable) semantics:
//   key_n = threefry2x32((0,42),(0,n)); bits = o0^o1 of tf(key_n,(0,2b+i));
//   u = max(tiny,(bitcast((bits>>9)|0x3F800000)-1)*(1-tiny)+tiny);
//   gumbel = -log(-log(u)); sample = argmax(log(p)+gumbel), tie -> 0.

namespace {

constexpr int NSTEPS = 128;
constexpr int HDIM = 128;
constexpr int G3H = 384;
constexpr int BT = 8;         // batch rows per block
constexpr int THREADS = 256;
constexpr int HP = 132;       // padded LDS row stride for h (16B aligned)
constexpr int SP = 516;       // padded LDS row stride for scratch

__device__ __forceinline__ float dot4(const float4 a, const float4 b, float c) {
  c = fmaf(a.x, b.x, c);
  c = fmaf(a.y, b.y, c);
  c = fmaf(a.z, b.z, c);
  c = fmaf(a.w, b.w, c);
  return c;
}

__device__ __forceinline__ void tf2x32(uint32_t k0, uint32_t k1,
                                       uint32_t x0, uint32_t x1,
                                       uint32_t& o0, uint32_t& o1) {
  const uint32_t ks2 = k0 ^ k1 ^ 0x1BD11BDAu;
  uint32_t v0 = x0 + k0;
  uint32_t v1 = x1 + k1;
  const uint32_t ks[3] = {k0, k1, ks2};
  const uint32_t rotA[4] = {13u, 15u, 26u, 6u};
  const uint32_t rotB[4] = {17u, 29u, 16u, 24u};
#pragma unroll
  for (int i = 0; i < 5; ++i) {
#pragma unroll
    for (int j = 0; j < 4; ++j) {
      const uint32_t r = (i & 1) ? rotB[j] : rotA[j];
      v0 += v1;
      v1 = (v1 << r) | (v1 >> (32u - r));
      v1 ^= v0;
    }
    v0 += ks[(i + 1) % 3];
    v1 += ks[(i + 2) % 3] + (uint32_t)(i + 1);
  }
  o0 = v0;
  o1 = v1;
}

__device__ __forceinline__ float u01_from_bits(uint32_t bits) {
  const float tiny = 1.1754943508222875e-38f;  // np.finfo(f32).tiny
  float f = __uint_as_float((bits >> 9) | 0x3F800000u) - 1.0f;
  float u = f * (1.0f - tiny) + tiny;
  return fmaxf(tiny, u);
}

__device__ __forceinline__ float sigmoidf(float x) {
  return 1.0f / (1.0f + expf(-x));
}

}  // namespace

extern "C" __global__ __launch_bounds__(256, 4)
void rnn_wavefn_kernel(const float* __restrict__ inputs,
                       const float* __restrict__ Wih0,
                       const float* __restrict__ Whh0,
                       const float* __restrict__ bih0,
                       const float* __restrict__ bhh0,
                       const float* __restrict__ Wih1,
                       const float* __restrict__ Whh1,
                       const float* __restrict__ bih1,
                       const float* __restrict__ bhh1,
                       const float* __restrict__ W1,
                       const float* __restrict__ b1,
                       const float* __restrict__ W2,
                       const float* __restrict__ b2,
                       float* __restrict__ out) {
  __shared__ float h1[BT][HP];
  __shared__ float h2[BT][HP];
  __shared__ float S[BT][SP];   // [0,384): gate scratch, [384,512): gi_n / hdn
  __shared__ float xin[BT][2];

  const int tid = threadIdx.x;
  const int b0 = blockIdx.x * BT;

  // GEMM-phase mapping: 64 j-threads x 4 q-threads; 6 j-rows x 2 batch rows.
  // Thread's batch rows: {tq, tq+4}. Within one LDS read instruction the wave
  // touches rows {0,1,2,3}+4i -> banks {0,4,8,12}+16i+k: conflict-free.
  const int tj = tid >> 2;        // 0..63
  const int tq = tid & 3;         // 0..3

  for (int i = tid; i < BT * HP; i += THREADS) {
    ((float*)h1)[i] = 0.0f;
    ((float*)h2)[i] = 0.0f;
  }
  if (tid < BT * 2) {
    xin[tid >> 1][tid & 1] = inputs[(b0 + (tid >> 1)) * 2 + (tid & 1)];
  }
  __syncthreads();

  for (int n = 0; n < NSTEPS; ++n) {
    const float* __restrict__ Wih0n = Wih0 + (size_t)n * G3H * 2;
    const float* __restrict__ Whh0n = Whh0 + (size_t)n * G3H * HDIM;
    const float* __restrict__ bih0n = bih0 + (size_t)n * G3H;
    const float* __restrict__ bhh0n = bhh0 + (size_t)n * G3H;
    const float* __restrict__ Wih1n = Wih1 + (size_t)n * G3H * HDIM;
    const float* __restrict__ Whh1n = Whh1 + (size_t)n * G3H * HDIM;
    const float* __restrict__ bih1n = bih1 + (size_t)n * G3H;
    const float* __restrict__ bhh1n = bhh1 + (size_t)n * G3H;
    const float* __restrict__ W1n = W1 + (size_t)n * HDIM * HDIM;
    const float* __restrict__ b1n = b1 + (size_t)n * HDIM;
    const float* __restrict__ W2n = W2 + (size_t)n * 2 * HDIM;
    const float* __restrict__ b2n = b2 + (size_t)n * 2;

    // ---------- GH0: S[b][j] = bhh0[j] + Whh0[j,:] . h1[b,:]
    {
      float acc[6][2];
#pragma unroll
      for (int g = 0; g < 6; ++g) {
        const float bias = bhh0n[tj + g * 64];
#pragma unroll
        for (int i = 0; i < 2; ++i) acc[g][i] = bias;
      }
      for (int kk = 0; kk < HDIM; kk += 16) {  // 16-float chunks: full 64B line use
#pragma unroll
        for (int s = 0; s < 4; ++s) {
          const int k = kk + s * 4;
          float4 w[6];
#pragma unroll
          for (int g = 0; g < 6; ++g)
            w[g] = *(const float4*)(Whh0n + (size_t)(tj + g * 64) * HDIM + k);
#pragma unroll
          for (int i = 0; i < 2; ++i) {
            const float4 hv = *(const float4*)&h1[tq + 4 * i][k];
#pragma unroll
            for (int g = 0; g < 6; ++g) acc[g][i] = dot4(w[g], hv, acc[g][i]);
          }
        }
      }
#pragma unroll
      for (int g = 0; g < 6; ++g)
#pragma unroll
        for (int i = 0; i < 2; ++i) S[tq + 4 * i][tj + g * 64] = acc[g][i];
    }
    __syncthreads();

    // ---------- C0: GRU0 combine -> h1   (gi from 2-wide x recomputed inline)
#pragma unroll
    for (int rep = 0; rep < (BT * HDIM) / THREADS; ++rep) {
      const int idx = tid + rep * THREADS;
      const int b = idx >> 7;
      const int d = idx & 127;
      const float x0 = xin[b][0];
      const float x1 = xin[b][1];
      const float gir = fmaf(Wih0n[d * 2 + 0], x0, fmaf(Wih0n[d * 2 + 1], x1, bih0n[d]));
      const float giz = fmaf(Wih0n[(d + 128) * 2 + 0], x0,
                             fmaf(Wih0n[(d + 128) * 2 + 1], x1, bih0n[d + 128]));
      const float gin = fmaf(Wih0n[(d + 256) * 2 + 0], x0,
                             fmaf(Wih0n[(d + 256) * 2 + 1], x1, bih0n[d + 256]));
      const float r = sigmoidf(gir + S[b][d]);
      const float z = sigmoidf(giz + S[b][d + 128]);
      const float nn = tanhf(gin + r * S[b][d + 256]);
      h1[b][d] = (1.0f - z) * nn + z * h1[b][d];
    }
    __syncthreads();

    // ---------- GH1a: S[b][j] = bhh1[j] + Whh1[j,:] . h2[b,:]
    {
      float acc[6][2];
#pragma unroll
      for (int g = 0; g < 6; ++g) {
        const float bias = bhh1n[tj + g * 64];
#pragma unroll
        for (int i = 0; i < 2; ++i) acc[g][i] = bias;
      }
      for (int kk = 0; kk < HDIM; kk += 16) {
#pragma unroll
        for (int s = 0; s < 4; ++s) {
          const int k = kk + s * 4;
          float4 w[6];
#pragma unroll
          for (int g = 0; g < 6; ++g)
            w[g] = *(const float4*)(Whh1n + (size_t)(tj + g * 64) * HDIM + k);
#pragma unroll
          for (int i = 0; i < 2; ++i) {
            const float4 hv = *(const float4*)&h2[tq + 4 * i][k];
#pragma unroll
            for (int g = 0; g < 6; ++g) acc[g][i] = dot4(w[g], hv, acc[g][i]);
          }
        }
      }
#pragma unroll
      for (int g = 0; g < 6; ++g)
#pragma unroll
        for (int i = 0; i < 2; ++i) S[tq + 4 * i][tj + g * 64] = acc[g][i];
    }
    // no barrier: GH1b touches exactly the same (thread -> S slot) ownership

    // ---------- GH1b: gi1 = bih1 + Wih1 . h1new; r,z summed into S, n kept
    // separate at S[b][row+128] (rows 256..383 -> slots 384..511).
    {
      float acc[6][2];
#pragma unroll
      for (int g = 0; g < 6; ++g) {
        const float bias = bih1n[tj + g * 64];
#pragma unroll
        for (int i = 0; i < 2; ++i) acc[g][i] = bias;
      }
      for (int kk = 0; kk < HDIM; kk += 16) {
#pragma unroll
        for (int s = 0; s < 4; ++s) {
          const int k = kk + s * 4;
          float4 w[6];
#pragma unroll
          for (int g = 0; g < 6; ++g)
            w[g] = *(const float4*)(Wih1n + (size_t)(tj + g * 64) * HDIM + k);
#pragma unroll
          for (int i = 0; i < 2; ++i) {
            const float4 hv = *(const float4*)&h1[tq + 4 * i][k];
#pragma unroll
            for (int g = 0; g < 6; ++g) acc[g][i] = dot4(w[g], hv, acc[g][i]);
          }
        }
      }
#pragma unroll
      for (int g = 0; g < 6; ++g) {
        const int row = tj + g * 64;
#pragma unroll
        for (int i = 0; i < 2; ++i) {
          if (row < 256) S[tq + 4 * i][row] += acc[g][i];      // r,z: gi+gh summed
          else           S[tq + 4 * i][row + 128] = acc[g][i]; // n: gi kept separate
        }
      }
    }
    __syncthreads();

    // ---------- C1: GRU1 combine -> h2, then s = cos(h2)+1e-10 into S[b][0..128)
#pragma unroll
    for (int rep = 0; rep < (BT * HDIM) / THREADS; ++rep) {
      const int idx = tid + rep * THREADS;
      const int b = idx >> 7;
      const int d = idx & 127;
      const float r = sigmoidf(S[b][d]);
      const float z = sigmoidf(S[b][d + 128]);
      const float nn = tanhf(S[b][d + 384] + r * S[b][d + 256]);
      const float h2n = (1.0f - z) * nn + z * h2[b][d];
      h2[b][d] = h2n;
      S[b][d] = cosf(h2n) + 1e-10f;  // only owner thread reads/writes this slot
    }
    __syncthreads();

    // ---------- HDN: S[b][384+d] = relu(b1[d] + W1[d,:] . s[b,:])
    {
      float acc[2][2];
#pragma unroll
      for (int g = 0; g < 2; ++g) {
        const float bias = b1n[tj + g * 64];
#pragma unroll
        for (int i = 0; i < 2; ++i) acc[g][i] = bias;
      }
      for (int kk = 0; kk < HDIM; kk += 16) {
#pragma unroll
        for (int s = 0; s < 4; ++s) {
          const int k = kk + s * 4;
          float4 w[2];
          w[0] = *(const float4*)(W1n + (size_t)(tj)*HDIM + k);
          w[1] = *(const float4*)(W1n + (size_t)(tj + 64) * HDIM + k);
#pragma unroll
          for (int i = 0; i < 2; ++i) {
            const float4 sv = *(const float4*)&S[tq + 4 * i][k];
            acc[0][i] = dot4(w[0], sv, acc[0][i]);
            acc[1][i] = dot4(w[1], sv, acc[1][i]);
          }
        }
      }
#pragma unroll
      for (int g = 0; g < 2; ++g)
#pragma unroll
        for (int i = 0; i < 2; ++i)
          S[tq + 4 * i][384 + tj + g * 64] = fmaxf(acc[g][i], 0.0f);
    }
    __syncthreads();

    // ---------- OUT: logits, softmax+1e-10, store p, threefry-gumbel sample
    if (tid < BT * 16) {
      const int lane = tid & 15;
      const int b = tid >> 4;
      const int kb = lane * 8;
      float a0 = 0.0f, a1 = 0.0f;
#pragma unroll
      for (int k = 0; k < 8; ++k) {
        const float hd = S[b][384 + kb + k];
        a0 = fmaf(W2n[kb + k], hd, a0);
        a1 = fmaf(W2n[HDIM + kb + k], hd, a1);
      }
#pragma unroll
      for (int off = 8; off >= 1; off >>= 1) {
        a0 += __shfl_xor(a0, off, 16);
        a1 += __shfl_xor(a1, off, 16);
      }
      if (lane == 0) {
        const float l0 = a0 + b2n[0];
        const float l1 = a1 + b2n[1];
        const float m = fmaxf(l0, l1);
        const float e0 = expf(l0 - m);
        const float e1 = expf(l1 - m);
        const float sum = e0 + e1;
        const float p0 = e0 / sum + 1e-10f;
        const float p1 = e1 / sum + 1e-10f;
        const int gb = b0 + b;
        out[((size_t)gb * NSTEPS + n) * 2 + 0] = p0;
        out[((size_t)gb * NSTEPS + n) * 2 + 1] = p1;

        uint32_t k0n, k1n;
        tf2x32(0u, 42u, 0u, (uint32_t)n, k0n, k1n);  // fold-like split of key(42)
        uint32_t o0, o1;
        tf2x32(k0n, k1n, 0u, (uint32_t)(2 * gb), o0, o1);
        const float u0 = u01_from_bits(o0 ^ o1);
        tf2x32(k0n, k1n, 0u, (uint32_t)(2 * gb + 1), o0, o1);
        const float u1 = u01_from_bits(o0 ^ o1);
        const float g0 = -logf(-logf(u0));
        const float g1 = -logf(-logf(u1));
        const float z0 = logf(p0) + g0;
        const float z1 = logf(p1) + g1;
        const int smp = (z1 > z0) ? 1 : 0;  // argmax, first index wins ties
        xin[b][0] = (smp == 0) ? 1.0f : 0.0f;
        xin[b][1] = (smp == 1) ? 1.0f : 0.0f;
      }
    }
    __syncthreads();
  }
}

extern "C" void kernel_launch(void* const* d_in, const int* in_sizes, int n_in,
                              void* d_out, int out_size, void* d_ws, size_t ws_size,
                              hipStream_t stream) {
  (void)in_sizes; (void)n_in; (void)out_size; (void)d_ws; (void)ws_size;
  const float* inputs = (const float*)d_in[0];
  const float* Wih0 = (const float*)d_in[1];
  const float* Whh0 = (const float*)d_in[2];
  const float* bih0 = (const float*)d_in[3];
  const float* bhh0 = (const float*)d_in[4];
  const float* Wih1 = (const float*)d_in[5];
  const float* Whh1 = (const float*)d_in[6];
  const float* bih1 = (const float*)d_in[7];
  const float* bhh1 = (const float*)d_in[8];
  const float* W1 = (const float*)d_in[9];
  const float* b1 = (const float*)d_in[10];
  const float* W2 = (const float*)d_in[11];
  const float* b2 = (const float*)d_in[12];
  float* out = (float*)d_out;

  const int nblocks = 8192 / BT;  // 1024 blocks, 4 per CU
  hipLaunchKernelGGL(rnn_wavefn_kernel, dim3(nblocks), dim3(THREADS), 0, stream,
                     inputs, Wih0, Whh0, bih0, bhh0, Wih1, Whh1, bih1, bhh1,
                     W1, b1, W2, b2, out);
}

// Round 3
// 7208.840 us; speedup vs baseline: 2.0190x; 2.0190x over previous
//
#include <hip/hip_runtime.h>
#include <cstdint>

// binary_disordered_RNNwavefunction: 128-step 2-layer GRU + MLP + softmax +
// threefry categorical sampling, B=8192, H=128, I=2.
//
// R3 = R1 config (BT=16, 512 blocks, 2 blocks/CU — the good L2-reuse,
// 16-FMA-per-weight-load balance) + conflict-free LDS row ownership.
//
// Row ownership (the only change vs R1): thread owns batch rows {tq + 4i},
// tq = tid&3, i=0..3. Per ds_read_b128 instruction (fixed i) the wave's 4
// distinct addresses are rows {0,1,2,3}+4i -> float-banks {0,4,8,12}+16i
// (stride 132 ≡ 4 mod 32): four disjoint 4-bank spans, conflict-free.
// R1's ownership {4q+i} gave spans {4i,16+4i} each twice -> 2-way b128
// conflict -> SQ_LDS_BANK_CONFLICT 8.85e8 (~17% of runtime).
//
// R2 lesson (do not revisit): BT=8 / 4 blocks/CU halves arithmetic
// intensity and desyncs 1024 blocks across steps -> L2 thrash (FETCH 647MB
// -> 4.4GB), latency collapse (VALUBusy 31%). Keep 2 blocks/CU, BT=16.
//
// RNG (verified): modern JAX (threefry_partitionable) semantics:
//   key_n = threefry2x32((0,42),(0,n)); bits = o0^o1 of tf(key_n,(0,2b+i));
//   u = max(tiny,(bitcast((bits>>9)|0x3F800000)-1)*(1-tiny)+tiny);
//   gumbel = -log(-log(u)); sample = argmax(log(p)+gumbel), tie -> 0.

namespace {

constexpr int NSTEPS = 128;
constexpr int HDIM = 128;
constexpr int G3H = 384;
constexpr int BT = 16;        // batch rows per block
constexpr int THREADS = 256;
constexpr int HP = 132;       // padded LDS row stride for h (16B aligned, ≡4 mod 32)
constexpr int SP = 516;       // padded LDS row stride for scratch (≡4 mod 32)

__device__ __forceinline__ float dot4(const float4 a, const float4 b, float c) {
  c = fmaf(a.x, b.x, c);
  c = fmaf(a.y, b.y, c);
  c = fmaf(a.z, b.z, c);
  c = fmaf(a.w, b.w, c);
  return c;
}

__device__ __forceinline__ void tf2x32(uint32_t k0, uint32_t k1,
                                       uint32_t x0, uint32_t x1,
                                       uint32_t& o0, uint32_t& o1) {
  const uint32_t ks2 = k0 ^ k1 ^ 0x1BD11BDAu;
  uint32_t v0 = x0 + k0;
  uint32_t v1 = x1 + k1;
  const uint32_t ks[3] = {k0, k1, ks2};
  const uint32_t rotA[4] = {13u, 15u, 26u, 6u};
  const uint32_t rotB[4] = {17u, 29u, 16u, 24u};
#pragma unroll
  for (int i = 0; i < 5; ++i) {
#pragma unroll
    for (int j = 0; j < 4; ++j) {
      const uint32_t r = (i & 1) ? rotB[j] : rotA[j];
      v0 += v1;
      v1 = (v1 << r) | (v1 >> (32u - r));
      v1 ^= v0;
    }
    v0 += ks[(i + 1) % 3];
    v1 += ks[(i + 2) % 3] + (uint32_t)(i + 1);
  }
  o0 = v0;
  o1 = v1;
}

__device__ __forceinline__ float u01_from_bits(uint32_t bits) {
  const float tiny = 1.1754943508222875e-38f;  // np.finfo(f32).tiny
  float f = __uint_as_float((bits >> 9) | 0x3F800000u) - 1.0f;
  float u = f * (1.0f - tiny) + tiny;
  return fmaxf(tiny, u);
}

__device__ __forceinline__ float sigmoidf(float x) {
  return 1.0f / (1.0f + expf(-x));
}

}  // namespace

extern "C" __global__ __launch_bounds__(256, 2)
void rnn_wavefn_kernel(const float* __restrict__ inputs,
                       const float* __restrict__ Wih0,
                       const float* __restrict__ Whh0,
                       const float* __restrict__ bih0,
                       const float* __restrict__ bhh0,
                       const float* __restrict__ Wih1,
                       const float* __restrict__ Whh1,
                       const float* __restrict__ bih1,
                       const float* __restrict__ bhh1,
                       const float* __restrict__ W1,
                       const float* __restrict__ b1,
                       const float* __restrict__ W2,
                       const float* __restrict__ b2,
                       float* __restrict__ out) {
  __shared__ float h1[BT][HP];
  __shared__ float h2[BT][HP];
  __shared__ float S[BT][SP];   // [0,384): gate scratch, [384,512): gi_n / hdn
  __shared__ float xin[BT][2];

  const int tid = threadIdx.x;
  const int b0 = blockIdx.x * BT;

  // GEMM-phase mapping: 64 j-threads x 4 q-threads; 6 j-rows x 4 batch rows.
  // Thread's batch rows: {tq + 4i} — conflict-free per instruction (see top).
  const int tj = tid >> 2;        // 0..63
  const int tq = tid & 3;         // 0..3

  for (int i = tid; i < BT * HP; i += THREADS) {
    ((float*)h1)[i] = 0.0f;
    ((float*)h2)[i] = 0.0f;
  }
  if (tid < BT * 2) {
    xin[tid >> 1][tid & 1] = inputs[(b0 + (tid >> 1)) * 2 + (tid & 1)];
  }
  __syncthreads();

  for (int n = 0; n < NSTEPS; ++n) {
    const float* __restrict__ Wih0n = Wih0 + (size_t)n * G3H * 2;
    const float* __restrict__ Whh0n = Whh0 + (size_t)n * G3H * HDIM;
    const float* __restrict__ bih0n = bih0 + (size_t)n * G3H;
    const float* __restrict__ bhh0n = bhh0 + (size_t)n * G3H;
    const float* __restrict__ Wih1n = Wih1 + (size_t)n * G3H * HDIM;
    const float* __restrict__ Whh1n = Whh1 + (size_t)n * G3H * HDIM;
    const float* __restrict__ bih1n = bih1 + (size_t)n * G3H;
    const float* __restrict__ bhh1n = bhh1 + (size_t)n * G3H;
    const float* __restrict__ W1n = W1 + (size_t)n * HDIM * HDIM;
    const float* __restrict__ b1n = b1 + (size_t)n * HDIM;
    const float* __restrict__ W2n = W2 + (size_t)n * 2 * HDIM;
    const float* __restrict__ b2n = b2 + (size_t)n * 2;

    // ---------- GH0: S[b][j] = bhh0[j] + Whh0[j,:] . h1[b,:]
    {
      float acc[6][4];
#pragma unroll
      for (int g = 0; g < 6; ++g) {
        const float bias = bhh0n[tj + g * 64];
#pragma unroll
        for (int i = 0; i < 4; ++i) acc[g][i] = bias;
      }
      for (int kk = 0; kk < HDIM; kk += 16) {  // 16-float chunks: full 64B line use
#pragma unroll
        for (int s = 0; s < 4; ++s) {
          const int k = kk + s * 4;
          float4 w[6];
#pragma unroll
          for (int g = 0; g < 6; ++g)
            w[g] = *(const float4*)(Whh0n + (size_t)(tj + g * 64) * HDIM + k);
#pragma unroll
          for (int i = 0; i < 4; ++i) {
            const float4 hv = *(const float4*)&h1[tq + 4 * i][k];
#pragma unroll
            for (int g = 0; g < 6; ++g) acc[g][i] = dot4(w[g], hv, acc[g][i]);
          }
        }
      }
#pragma unroll
      for (int g = 0; g < 6; ++g)
#pragma unroll
        for (int i = 0; i < 4; ++i) S[tq + 4 * i][tj + g * 64] = acc[g][i];
    }
    __syncthreads();

    // ---------- C0: GRU0 combine -> h1   (gi from 2-wide x recomputed inline)
#pragma unroll
    for (int rep = 0; rep < (BT * HDIM) / THREADS; ++rep) {
      const int idx = tid + rep * THREADS;
      const int b = idx >> 7;
      const int d = idx & 127;
      const float x0 = xin[b][0];
      const float x1 = xin[b][1];
      const float gir = fmaf(Wih0n[d * 2 + 0], x0, fmaf(Wih0n[d * 2 + 1], x1, bih0n[d]));
      const float giz = fmaf(Wih0n[(d + 128) * 2 + 0], x0,
                             fmaf(Wih0n[(d + 128) * 2 + 1], x1, bih0n[d + 128]));
      const float gin = fmaf(Wih0n[(d + 256) * 2 + 0], x0,
                             fmaf(Wih0n[(d + 256) * 2 + 1], x1, bih0n[d + 256]));
      const float r = sigmoidf(gir + S[b][d]);
      const float z = sigmoidf(giz + S[b][d + 128]);
      const float nn = tanhf(gin + r * S[b][d + 256]);
      h1[b][d] = (1.0f - z) * nn + z * h1[b][d];
    }
    __syncthreads();

    // ---------- GH1a: S[b][j] = bhh1[j] + Whh1[j,:] . h2[b,:]
    {
      float acc[6][4];
#pragma unroll
      for (int g = 0; g < 6; ++g) {
        const float bias = bhh1n[tj + g * 64];
#pragma unroll
        for (int i = 0; i < 4; ++i) acc[g][i] = bias;
      }
      for (int kk = 0; kk < HDIM; kk += 16) {
#pragma unroll
        for (int s = 0; s < 4; ++s) {
          const int k = kk + s * 4;
          float4 w[6];
#pragma unroll
          for (int g = 0; g < 6; ++g)
            w[g] = *(const float4*)(Whh1n + (size_t)(tj + g * 64) * HDIM + k);
#pragma unroll
          for (int i = 0; i < 4; ++i) {
            const float4 hv = *(const float4*)&h2[tq + 4 * i][k];
#pragma unroll
            for (int g = 0; g < 6; ++g) acc[g][i] = dot4(w[g], hv, acc[g][i]);
          }
        }
      }
#pragma unroll
      for (int g = 0; g < 6; ++g)
#pragma unroll
        for (int i = 0; i < 4; ++i) S[tq + 4 * i][tj + g * 64] = acc[g][i];
    }
    // no barrier: GH1b touches exactly the same (thread -> S slot) ownership

    // ---------- GH1b: gi1 = bih1 + Wih1 . h1new; r,z summed into S, n kept
    // separate at S[b][row+128] (rows 256..383 -> slots 384..511).
    {
      float acc[6][4];
#pragma unroll
      for (int g = 0; g < 6; ++g) {
        const float bias = bih1n[tj + g * 64];
#pragma unroll
        for (int i = 0; i < 4; ++i) acc[g][i] = bias;
      }
      for (int kk = 0; kk < HDIM; kk += 16) {
#pragma unroll
        for (int s = 0; s < 4; ++s) {
          const int k = kk + s * 4;
          float4 w[6];
#pragma unroll
          for (int g = 0; g < 6; ++g)
            w[g] = *(const float4*)(Wih1n + (size_t)(tj + g * 64) * HDIM + k);
#pragma unroll
          for (int i = 0; i < 4; ++i) {
            const float4 hv = *(const float4*)&h1[tq + 4 * i][k];
#pragma unroll
            for (int g = 0; g < 6; ++g) acc[g][i] = dot4(w[g], hv, acc[g][i]);
          }
        }
      }
#pragma unroll
      for (int g = 0; g < 6; ++g) {
        const int row = tj + g * 64;
#pragma unroll
        for (int i = 0; i < 4; ++i) {
          if (row < 256) S[tq + 4 * i][row] += acc[g][i];      // r,z: gi+gh summed
          else           S[tq + 4 * i][row + 128] = acc[g][i]; // n: gi kept separate
        }
      }
    }
    __syncthreads();

    // ---------- C1: GRU1 combine -> h2, then s = cos(h2)+1e-10 into S[b][0..128)
#pragma unroll
    for (int rep = 0; rep < (BT * HDIM) / THREADS; ++rep) {
      const int idx = tid + rep * THREADS;
      const int b = idx >> 7;
      const int d = idx & 127;
      const float r = sigmoidf(S[b][d]);
      const float z = sigmoidf(S[b][d + 128]);
      const float nn = tanhf(S[b][d + 384] + r * S[b][d + 256]);
      const float h2n = (1.0f - z) * nn + z * h2[b][d];
      h2[b][d] = h2n;
      S[b][d] = cosf(h2n) + 1e-10f;  // only owner thread reads/writes this slot
    }
    __syncthreads();

    // ---------- HDN: S[b][384+d] = relu(b1[d] + W1[d,:] . s[b,:])
    {
      float acc[2][4];
#pragma unroll
      for (int g = 0; g < 2; ++g) {
        const float bias = b1n[tj + g * 64];
#pragma unroll
        for (int i = 0; i < 4; ++i) acc[g][i] = bias;
      }
      for (int kk = 0; kk < HDIM; kk += 16) {
#pragma unroll
        for (int s = 0; s < 4; ++s) {
          const int k = kk + s * 4;
          float4 w[2];
          w[0] = *(const float4*)(W1n + (size_t)(tj)*HDIM + k);
          w[1] = *(const float4*)(W1n + (size_t)(tj + 64) * HDIM + k);
#pragma unroll
          for (int i = 0; i < 4; ++i) {
            const float4 sv = *(const float4*)&S[tq + 4 * i][k];
            acc[0][i] = dot4(w[0], sv, acc[0][i]);
            acc[1][i] = dot4(w[1], sv, acc[1][i]);
          }
        }
      }
#pragma unroll
      for (int g = 0; g < 2; ++g)
#pragma unroll
        for (int i = 0; i < 4; ++i)
          S[tq + 4 * i][384 + tj + g * 64] = fmaxf(acc[g][i], 0.0f);
    }
    __syncthreads();

    // ---------- OUT: logits, softmax+1e-10, store p, threefry-gumbel sample
    {
      const int lane = tid & 15;
      const int b = tid >> 4;
      const int kb = lane * 8;
      float a0 = 0.0f, a1 = 0.0f;
#pragma unroll
      for (int k = 0; k < 8; ++k) {
        const float hd = S[b][384 + kb + k];
        a0 = fmaf(W2n[kb + k], hd, a0);
        a1 = fmaf(W2n[HDIM + kb + k], hd, a1);
      }
#pragma unroll
      for (int off = 8; off >= 1; off >>= 1) {
        a0 += __shfl_xor(a0, off, 16);
        a1 += __shfl_xor(a1, off, 16);
      }
      if (lane == 0) {
        const float l0 = a0 + b2n[0];
        const float l1 = a1 + b2n[1];
        const float m = fmaxf(l0, l1);
        const float e0 = expf(l0 - m);
        const float e1 = expf(l1 - m);
        const float sum = e0 + e1;
        const float p0 = e0 / sum + 1e-10f;
        const float p1 = e1 / sum + 1e-10f;
        const int gb = b0 + b;
        out[((size_t)gb * NSTEPS + n) * 2 + 0] = p0;
        out[((size_t)gb * NSTEPS + n) * 2 + 1] = p1;

        uint32_t k0n, k1n;
        tf2x32(0u, 42u, 0u, (uint32_t)n, k0n, k1n);  // fold-like split of key(42)
        uint32_t o0, o1;
        tf2x32(k0n, k1n, 0u, (uint32_t)(2 * gb), o0, o1);
        const float u0 = u01_from_bits(o0 ^ o1);
        tf2x32(k0n, k1n, 0u, (uint32_t)(2 * gb + 1), o0, o1);
        const float u1 = u01_from_bits(o0 ^ o1);
        const float g0 = -logf(-logf(u0));
        const float g1 = -logf(-logf(u1));
        const float z0 = logf(p0) + g0;
        const float z1 = logf(p1) + g1;
        const int smp = (z1 > z0) ? 1 : 0;  // argmax, first index wins ties
        xin[b][0] = (smp == 0) ? 1.0f : 0.0f;
        xin[b][1] = (smp == 1) ? 1.0f : 0.0f;
      }
    }
    __syncthreads();
  }
}

extern "C" void kernel_launch(void* const* d_in, const int* in_sizes, int n_in,
                              void* d_out, int out_size, void* d_ws, size_t ws_size,
                              hipStream_t stream) {
  (void)in_sizes; (void)n_in; (void)out_size; (void)d_ws; (void)ws_size;
  const float* inputs = (const float*)d_in[0];
  const float* Wih0 = (const float*)d_in[1];
  const float* Whh0 = (const float*)d_in[2];
  const float* bih0 = (const float*)d_in[3];
  const float* bhh0 = (const float*)d_in[4];
  const float* Wih1 = (const float*)d_in[5];
  const float* Whh1 = (const float*)d_in[6];
  const float* bih1 = (const float*)d_in[7];
  const float* bhh1 = (const float*)d_in[8];
  const float* W1 = (const float*)d_in[9];
  const float* b1 = (const float*)d_in[10];
  const float* W2 = (const float*)d_in[11];
  const float* b2 = (const float*)d_in[12];
  float* out = (float*)d_out;

  const int nblocks = 8192 / BT;  // 512 blocks, 2 per CU
  hipLaunchKernelGGL(rnn_wavefn_kernel, dim3(nblocks), dim3(THREADS), 0, stream,
                     inputs, Wih0, Whh0, bih0, bhh0, Wih1, Whh1, bih1, bhh1,
                     W1, b1, W2, b2, out);
}

// Round 4
// 4382.044 us; speedup vs baseline: 3.3214x; 1.6451x over previous
//
#include <hip/hip_runtime.h>
#include <cstdint>

// binary_disordered_RNNwavefunction: 128-step 2-layer GRU + MLP + softmax +
// threefry categorical sampling, B=8192, H=128, I=2.
//
// R4: GEMMs moved to MFMA (f32_16x16x32_f16) with fp32-exact-class numerics
// via 2-term fp16 split: a = a1 + a2s/4096, a1 = f16(a), a2s = f16((a-a1)*4096).
// Per tile 3 MFMAs: acc1 += A1*B1; acc2 += A1*B2s + A2s*B1 (acc2 is x4096-
// scaled); dropped A2s*B2s term ~3e-8 absolute on gates (fp32-reorder class,
// flip-safe per R1-R3 evidence). Weights pre-split per launch into fragment-
// layout f16 arrays in d_ws (80 MiB); falls back to the proven R3 fp32 kernel
// if ws_size is too small.
//
// Fragment layouts (16x16x32, m89/m97-verified conventions):
//   A: lane L holds A[m = L&15][k = kt*32 + (L>>4)*8 + j], j=0..7
//   B: lane L holds B[k = kt*32 + (L>>4)*8 + j][n = ntile*16 + (L&15)]
//   D: lane L reg r holds C[m = (L>>4)*4 + r][n = ntile*16 + (L&15)]
// h/cos are stored in LDS in A-scatter layout [kt][lane][8] so GEMM waves do
// conflict-free ds_read_b128 at base + lane*16B; combine phases (remapped to
// b = idx&15, d = idx>>4) write that layout conflict-free.
//
// R2 lesson: keep BT=16, 512 blocks, 2 blocks/CU (L2 lockstep + AI).
// RNG (verified): modern JAX threefry_partitionable semantics.

namespace {

constexpr int NSTEPS = 128;
constexpr int HDIM = 128;
constexpr int G3H = 384;
constexpr int BT = 16;
constexpr int THREADS = 256;
constexpr int HP = 132;       // fp32 h row stride
constexpr int SP = 516;       // S row stride

typedef _Float16 half8 __attribute__((ext_vector_type(8)));
typedef float f32x4 __attribute__((ext_vector_type(4)));

constexpr float LO_SCALE = 4096.0f;
constexpr float LO_INV = 2.44140625e-4f;   // 1/4096
constexpr float F16_MIN_NORM = 6.104e-5f;

__device__ __forceinline__ void split_f16(float x, _Float16& a1, _Float16& a2s) {
  // if |x| below f16 normal range, route everything through the scaled lo part
  _Float16 h = (fabsf(x) < F16_MIN_NORM) ? (_Float16)0.0f : (_Float16)x;
  a1 = h;
  a2s = (_Float16)((x - (float)h) * LO_SCALE);
}

__device__ __forceinline__ void tf2x32(uint32_t k0, uint32_t k1,
                                       uint32_t x0, uint32_t x1,
                                       uint32_t& o0, uint32_t& o1) {
  const uint32_t ks2 = k0 ^ k1 ^ 0x1BD11BDAu;
  uint32_t v0 = x0 + k0;
  uint32_t v1 = x1 + k1;
  const uint32_t ks[3] = {k0, k1, ks2};
  const uint32_t rotA[4] = {13u, 15u, 26u, 6u};
  const uint32_t rotB[4] = {17u, 29u, 16u, 24u};
#pragma unroll
  for (int i = 0; i < 5; ++i) {
#pragma unroll
    for (int j = 0; j < 4; ++j) {
      const uint32_t r = (i & 1) ? rotB[j] : rotA[j];
      v0 += v1;
      v1 = (v1 << r) | (v1 >> (32u - r));
      v1 ^= v0;
    }
    v0 += ks[(i + 1) % 3];
    v1 += ks[(i + 2) % 3] + (uint32_t)(i + 1);
  }
  o0 = v0;
  o1 = v1;
}

__device__ __forceinline__ float u01_from_bits(uint32_t bits) {
  const float tiny = 1.1754943508222875e-38f;
  float f = __uint_as_float((bits >> 9) | 0x3F800000u) - 1.0f;
  float u = f * (1.0f - tiny) + tiny;
  return fmaxf(tiny, u);
}

__device__ __forceinline__ float sigmoidf(float x) {
  return 1.0f / (1.0f + expf(-x));
}

__device__ __forceinline__ float dot4(const float4 a, const float4 b, float c) {
  c = fmaf(a.x, b.x, c);
  c = fmaf(a.y, b.y, c);
  c = fmaf(a.z, b.z, c);
  c = fmaf(a.w, b.w, c);
  return c;
}

}  // namespace

// ---------------------------------------------------------------------------
// Preprocess: fp32 W[n][JT*16][128] -> frag-layout split-f16 arrays
// dst index: (((n*JT + jt)*4 + kt)*64 + lane)*8 + j
// where elem = W[n][jt*16 + (lane&15)][kt*32 + (lane>>4)*8 + j]
// ---------------------------------------------------------------------------
extern "C" __global__ __launch_bounds__(256)
void preprocess_split_kernel(const float* __restrict__ src,
                             _Float16* __restrict__ d1,
                             _Float16* __restrict__ d2,
                             int total, int JT) {
  const int idx = blockIdx.x * 256 + threadIdx.x;
  if (idx >= total) return;
  const int lane = idx & 63;
  const int kt = (idx >> 6) & 3;
  const int rest = idx >> 8;
  const int jt = rest % JT;
  const int nstep = rest / JT;

  const int j = jt * 16 + (lane & 15);
  const int k0 = kt * 32 + ((lane >> 4) << 3);
  const float* p = src + ((size_t)nstep * (JT * 16) + j) * 128 + k0;
  const float4 w0 = *(const float4*)p;
  const float4 w1 = *(const float4*)(p + 4);
  const float xs[8] = {w0.x, w0.y, w0.z, w0.w, w1.x, w1.y, w1.z, w1.w};

  half8 o1, o2;
#pragma unroll
  for (int t = 0; t < 8; ++t) {
    _Float16 a1, a2s;
    split_f16(xs[t], a1, a2s);
    o1[t] = a1;
    o2[t] = a2s;
  }
  *(half8*)(d1 + (size_t)idx * 8) = o1;
  *(half8*)(d2 + (size_t)idx * 8) = o2;
}

// ---------------------------------------------------------------------------
// Main MFMA kernel
// ---------------------------------------------------------------------------
extern "C" __global__ __launch_bounds__(256, 2)
void rnn_wavefn_mfma_kernel(const float* __restrict__ inputs,
                            const float* __restrict__ Wih0,
                            const float* __restrict__ bih0,
                            const float* __restrict__ bhh0,
                            const float* __restrict__ bih1,
                            const float* __restrict__ bhh1,
                            const float* __restrict__ b1,
                            const float* __restrict__ W2,
                            const float* __restrict__ b2,
                            const _Float16* __restrict__ Whh0_1,
                            const _Float16* __restrict__ Whh0_2,
                            const _Float16* __restrict__ Wih1_1,
                            const _Float16* __restrict__ Wih1_2,
                            const _Float16* __restrict__ Whh1_1,
                            const _Float16* __restrict__ Whh1_2,
                            const _Float16* __restrict__ W1_1,
                            const _Float16* __restrict__ W1_2,
                            float* __restrict__ out) {
  __shared__ float S[BT][SP];          // gates / hdn scratch (R3 convention)
  __shared__ float h1f[BT][HP];        // fp32 state (row-major)
  __shared__ float h2f[BT][HP];
  __shared__ _Float16 h1A1[2048], h1A2[2048];   // A-scatter split layouts
  __shared__ _Float16 h2A1[2048], h2A2[2048];
  __shared__ _Float16 csA1[2048], csA2[2048];
  __shared__ float xin[BT][2];

  const int tid = threadIdx.x;
  const int b0 = blockIdx.x * BT;
  const int wv = tid >> 6;        // wave 0..3
  const int lane = tid & 63;
  const int lm = lane & 15;       // n-col within tile / D col
  const int m0 = (lane >> 4) * 4; // D row base

  for (int i = tid; i < BT * HP; i += THREADS) {
    ((float*)h1f)[i] = 0.0f;
    ((float*)h2f)[i] = 0.0f;
  }
  for (int i = tid; i < 2048; i += THREADS) {
    h1A1[i] = (_Float16)0.0f; h1A2[i] = (_Float16)0.0f;
    h2A1[i] = (_Float16)0.0f; h2A2[i] = (_Float16)0.0f;
  }
  if (tid < BT * 2) {
    xin[tid >> 1][tid & 1] = inputs[(b0 + (tid >> 1)) * 2 + (tid & 1)];
  }
  __syncthreads();

  for (int n = 0; n < NSTEPS; ++n) {
    const float* __restrict__ Wih0n = Wih0 + (size_t)n * G3H * 2;
    const float* __restrict__ bih0n = bih0 + (size_t)n * G3H;
    const float* __restrict__ bhh0n = bhh0 + (size_t)n * G3H;
    const float* __restrict__ bih1n = bih1 + (size_t)n * G3H;
    const float* __restrict__ bhh1n = bhh1 + (size_t)n * G3H;
    const float* __restrict__ b1n = b1 + (size_t)n * HDIM;
    const float* __restrict__ W2n = W2 + (size_t)n * 2 * HDIM;
    const float* __restrict__ b2n = b2 + (size_t)n * 2;
    const size_t fo3 = (size_t)n * 49152;   // 24*4*64*8 frag elems per step
    const size_t fo1 = (size_t)n * 16384;   // 8*4*64*8

    // ---------- GH0: S[b][j] = bhh0[j] + Whh0[j,:] . h1[b,:]  (MFMA)
    {
      half8 A1[4], A2[4];
#pragma unroll
      for (int kt = 0; kt < 4; ++kt) {
        A1[kt] = *(const half8*)&h1A1[(kt * 64 + lane) * 8];
        A2[kt] = *(const half8*)&h1A2[(kt * 64 + lane) * 8];
      }
      const _Float16* B1 = Whh0_1 + fo3;
      const _Float16* B2 = Whh0_2 + fo3;
#pragma unroll
      for (int t = 0; t < 6; ++t) {
        const int jt = wv * 6 + t;
        f32x4 c1 = {0.f, 0.f, 0.f, 0.f}, c2 = {0.f, 0.f, 0.f, 0.f};
#pragma unroll
        for (int kt = 0; kt < 4; ++kt) {
          const size_t o = ((size_t)(jt * 4 + kt) * 64 + lane) * 8;
          const half8 b1v = *(const half8*)(B1 + o);
          const half8 b2v = *(const half8*)(B2 + o);
          c1 = __builtin_amdgcn_mfma_f32_16x16x32_f16(A1[kt], b1v, c1, 0, 0, 0);
          c2 = __builtin_amdgcn_mfma_f32_16x16x32_f16(A1[kt], b2v, c2, 0, 0, 0);
          c2 = __builtin_amdgcn_mfma_f32_16x16x32_f16(A2[kt], b1v, c2, 0, 0, 0);
        }
        const int col = jt * 16 + lm;
        const float bias = bhh0n[col];
#pragma unroll
        for (int r = 0; r < 4; ++r)
          S[m0 + r][col] = bias + fmaf(c2[r], LO_INV, c1[r]);
      }
    }
    __syncthreads();

    // ---------- C0: GRU0 combine -> h1 (fp32 + split-f16 A-layout)
#pragma unroll
    for (int rep = 0; rep < (BT * HDIM) / THREADS; ++rep) {
      const int idx = tid + rep * THREADS;
      const int b = idx & 15;
      const int d = idx >> 4;
      const float x0 = xin[b][0];
      const float x1 = xin[b][1];
      const float gir = fmaf(Wih0n[d * 2 + 0], x0, fmaf(Wih0n[d * 2 + 1], x1, bih0n[d]));
      const float giz = fmaf(Wih0n[(d + 128) * 2 + 0], x0,
                             fmaf(Wih0n[(d + 128) * 2 + 1], x1, bih0n[d + 128]));
      const float gin = fmaf(Wih0n[(d + 256) * 2 + 0], x0,
                             fmaf(Wih0n[(d + 256) * 2 + 1], x1, bih0n[d + 256]));
      const float r = sigmoidf(gir + S[b][d]);
      const float z = sigmoidf(giz + S[b][d + 128]);
      const float nn = tanhf(gin + r * S[b][d + 256]);
      const float h1n = (1.0f - z) * nn + z * h1f[b][d];
      h1f[b][d] = h1n;
      const int si = (((d >> 5) << 6) + (((d >> 3) & 3) << 4) + b) * 8 + (d & 7);
      _Float16 a1, a2s;
      split_f16(h1n, a1, a2s);
      h1A1[si] = a1;
      h1A2[si] = a2s;
    }
    __syncthreads();

    // ---------- GH1a+GH1b fused (MFMA): r,z gates summed in-accumulator;
    // n-gate parts kept separate (gh_n -> S[.][col], gi_n -> S[.][col+128]).
    {
      half8 P1[4], P2[4], Q1[4], Q2[4];   // P = h2(old), Q = h1(new)
#pragma unroll
      for (int kt = 0; kt < 4; ++kt) {
        P1[kt] = *(const half8*)&h2A1[(kt * 64 + lane) * 8];
        P2[kt] = *(const half8*)&h2A2[(kt * 64 + lane) * 8];
        Q1[kt] = *(const half8*)&h1A1[(kt * 64 + lane) * 8];
        Q2[kt] = *(const half8*)&h1A2[(kt * 64 + lane) * 8];
      }
      const _Float16* Ba1 = Whh1_1 + fo3;
      const _Float16* Ba2 = Whh1_2 + fo3;
      const _Float16* Bb1 = Wih1_1 + fo3;
      const _Float16* Bb2 = Wih1_2 + fo3;
#pragma unroll
      for (int t = 0; t < 6; ++t) {
        const int jt = wv * 6 + t;
        const int col = jt * 16 + lm;
        if (jt < 16) {   // r,z columns: sum gi+gh in the same accumulators
          f32x4 c1 = {0.f, 0.f, 0.f, 0.f}, c2 = {0.f, 0.f, 0.f, 0.f};
#pragma unroll
          for (int kt = 0; kt < 4; ++kt) {
            const size_t o = ((size_t)(jt * 4 + kt) * 64 + lane) * 8;
            const half8 ba1 = *(const half8*)(Ba1 + o);
            const half8 ba2 = *(const half8*)(Ba2 + o);
            const half8 bb1 = *(const half8*)(Bb1 + o);
            const half8 bb2 = *(const half8*)(Bb2 + o);
            c1 = __builtin_amdgcn_mfma_f32_16x16x32_f16(P1[kt], ba1, c1, 0, 0, 0);
            c2 = __builtin_amdgcn_mfma_f32_16x16x32_f16(P1[kt], ba2, c2, 0, 0, 0);
            c2 = __builtin_amdgcn_mfma_f32_16x16x32_f16(P2[kt], ba1, c2, 0, 0, 0);
            c1 = __builtin_amdgcn_mfma_f32_16x16x32_f16(Q1[kt], bb1, c1, 0, 0, 0);
            c2 = __builtin_amdgcn_mfma_f32_16x16x32_f16(Q1[kt], bb2, c2, 0, 0, 0);
            c2 = __builtin_amdgcn_mfma_f32_16x16x32_f16(Q2[kt], bb1, c2, 0, 0, 0);
          }
          const float bias = bhh1n[col] + bih1n[col];
#pragma unroll
          for (int r = 0; r < 4; ++r)
            S[m0 + r][col] = bias + fmaf(c2[r], LO_INV, c1[r]);
        } else {         // n columns: keep gh_n and gi_n separate
          f32x4 ca1 = {0.f, 0.f, 0.f, 0.f}, ca2 = {0.f, 0.f, 0.f, 0.f};
          f32x4 cb1 = {0.f, 0.f, 0.f, 0.f}, cb2 = {0.f, 0.f, 0.f, 0.f};
#pragma unroll
          for (int kt = 0; kt < 4; ++kt) {
            const size_t o = ((size_t)(jt * 4 + kt) * 64 + lane) * 8;
            const half8 ba1 = *(const half8*)(Ba1 + o);
            const half8 ba2 = *(const half8*)(Ba2 + o);
            const half8 bb1 = *(const half8*)(Bb1 + o);
            const half8 bb2 = *(const half8*)(Bb2 + o);
            ca1 = __builtin_amdgcn_mfma_f32_16x16x32_f16(P1[kt], ba1, ca1, 0, 0, 0);
            ca2 = __builtin_amdgcn_mfma_f32_16x16x32_f16(P1[kt], ba2, ca2, 0, 0, 0);
            ca2 = __builtin_amdgcn_mfma_f32_16x16x32_f16(P2[kt], ba1, ca2, 0, 0, 0);
            cb1 = __builtin_amdgcn_mfma_f32_16x16x32_f16(Q1[kt], bb1, cb1, 0, 0, 0);
            cb2 = __builtin_amdgcn_mfma_f32_16x16x32_f16(Q1[kt], bb2, cb2, 0, 0, 0);
            cb2 = __builtin_amdgcn_mfma_f32_16x16x32_f16(Q2[kt], bb1, cb2, 0, 0, 0);
          }
          const float biasA = bhh1n[col];
          const float biasB = bih1n[col];
#pragma unroll
          for (int r = 0; r < 4; ++r) {
            S[m0 + r][col] = biasA + fmaf(ca2[r], LO_INV, ca1[r]);        // gh_n
            S[m0 + r][col + 128] = biasB + fmaf(cb2[r], LO_INV, cb1[r]);  // gi_n
          }
        }
      }
    }
    __syncthreads();

    // ---------- C1: GRU1 combine -> h2; cos -> split A-layout
#pragma unroll
    for (int rep = 0; rep < (BT * HDIM) / THREADS; ++rep) {
      const int idx = tid + rep * THREADS;
      const int b = idx & 15;
      const int d = idx >> 4;
      const float r = sigmoidf(S[b][d]);
      const float z = sigmoidf(S[b][d + 128]);
      const float nn = tanhf(S[b][d + 384] + r * S[b][d + 256]);
      const float h2n = (1.0f - z) * nn + z * h2f[b][d];
      h2f[b][d] = h2n;
      const int si = (((d >> 5) << 6) + (((d >> 3) & 3) << 4) + b) * 8 + (d & 7);
      _Float16 a1, a2s;
      split_f16(h2n, a1, a2s);
      h2A1[si] = a1;
      h2A2[si] = a2s;
      const float cv = cosf(h2n) + 1e-10f;
      split_f16(cv, a1, a2s);
      csA1[si] = a1;
      csA2[si] = a2s;
    }
    __syncthreads();

    // ---------- HDN: S[b][384+d] = relu(b1[d] + W1[d,:] . cos[b,:])  (MFMA)
    {
      half8 A1[4], A2[4];
#pragma unroll
      for (int kt = 0; kt < 4; ++kt) {
        A1[kt] = *(const half8*)&csA1[(kt * 64 + lane) * 8];
        A2[kt] = *(const half8*)&csA2[(kt * 64 + lane) * 8];
      }
      const _Float16* B1 = W1_1 + fo1;
      const _Float16* B2 = W1_2 + fo1;
#pragma unroll
      for (int t = 0; t < 2; ++t) {
        const int jt = wv * 2 + t;
        f32x4 c1 = {0.f, 0.f, 0.f, 0.f}, c2 = {0.f, 0.f, 0.f, 0.f};
#pragma unroll
        for (int kt = 0; kt < 4; ++kt) {
          const size_t o = ((size_t)(jt * 4 + kt) * 64 + lane) * 8;
          const half8 b1v = *(const half8*)(B1 + o);
          const half8 b2v = *(const half8*)(B2 + o);
          c1 = __builtin_amdgcn_mfma_f32_16x16x32_f16(A1[kt], b1v, c1, 0, 0, 0);
          c2 = __builtin_amdgcn_mfma_f32_16x16x32_f16(A1[kt], b2v, c2, 0, 0, 0);
          c2 = __builtin_amdgcn_mfma_f32_16x16x32_f16(A2[kt], b1v, c2, 0, 0, 0);
        }
        const int col = jt * 16 + lm;
        const float bias = b1n[col];
#pragma unroll
        for (int r = 0; r < 4; ++r)
          S[m0 + r][384 + col] = fmaxf(bias + fmaf(c2[r], LO_INV, c1[r]), 0.0f);
      }
    }
    __syncthreads();

    // ---------- OUT: logits, softmax+1e-10, store p, threefry-gumbel sample
    {
      const int ln = tid & 15;
      const int b = tid >> 4;
      const int kb = ln * 8;
      float a0 = 0.0f, a1 = 0.0f;
#pragma unroll
      for (int k = 0; k < 8; ++k) {
        const float hd = S[b][384 + kb + k];
        a0 = fmaf(W2n[kb + k], hd, a0);
        a1 = fmaf(W2n[HDIM + kb + k], hd, a1);
      }
#pragma unroll
      for (int off = 8; off >= 1; off >>= 1) {
        a0 += __shfl_xor(a0, off, 16);
        a1 += __shfl_xor(a1, off, 16);
      }
      if (ln == 0) {
        const float l0 = a0 + b2n[0];
        const float l1 = a1 + b2n[1];
        const float m = fmaxf(l0, l1);
        const float e0 = expf(l0 - m);
        const float e1 = expf(l1 - m);
        const float sum = e0 + e1;
        const float p0 = e0 / sum + 1e-10f;
        const float p1 = e1 / sum + 1e-10f;
        const int gb = b0 + b;
        out[((size_t)gb * NSTEPS + n) * 2 + 0] = p0;
        out[((size_t)gb * NSTEPS + n) * 2 + 1] = p1;

        uint32_t k0n, k1n;
        tf2x32(0u, 42u, 0u, (uint32_t)n, k0n, k1n);
        uint32_t o0, o1;
        tf2x32(k0n, k1n, 0u, (uint32_t)(2 * gb), o0, o1);
        const float u0 = u01_from_bits(o0 ^ o1);
        tf2x32(k0n, k1n, 0u, (uint32_t)(2 * gb + 1), o0, o1);
        const float u1 = u01_from_bits(o0 ^ o1);
        const float g0 = -logf(-logf(u0));
        const float g1 = -logf(-logf(u1));
        const float z0 = logf(p0) + g0;
        const float z1 = logf(p1) + g1;
        const int smp = (z1 > z0) ? 1 : 0;
        xin[b][0] = (smp == 0) ? 1.0f : 0.0f;
        xin[b][1] = (smp == 1) ? 1.0f : 0.0f;
      }
    }
    __syncthreads();
  }
}

// ---------------------------------------------------------------------------
// Fallback: R3 fp32-VALU kernel (proven, 7.2 ms) — used if ws too small.
// ---------------------------------------------------------------------------
extern "C" __global__ __launch_bounds__(256, 2)
void rnn_wavefn_fp32_kernel(const float* __restrict__ inputs,
                            const float* __restrict__ Wih0,
                            const float* __restrict__ Whh0,
                            const float* __restrict__ bih0,
                            const float* __restrict__ bhh0,
                            const float* __restrict__ Wih1,
                            const float* __restrict__ Whh1,
                            const float* __restrict__ bih1,
                            const float* __restrict__ bhh1,
                            const float* __restrict__ W1,
                            const float* __restrict__ b1,
                            const float* __restrict__ W2,
                            const float* __restrict__ b2,
                            float* __restrict__ out) {
  __shared__ float h1[BT][HP];
  __shared__ float h2[BT][HP];
  __shared__ float S[BT][SP];
  __shared__ float xin[BT][2];

  const int tid = threadIdx.x;
  const int b0 = blockIdx.x * BT;
  const int tj = tid >> 2;
  const int tq = tid & 3;

  for (int i = tid; i < BT * HP; i += THREADS) {
    ((float*)h1)[i] = 0.0f;
    ((float*)h2)[i] = 0.0f;
  }
  if (tid < BT * 2) {
    xin[tid >> 1][tid & 1] = inputs[(b0 + (tid >> 1)) * 2 + (tid & 1)];
  }
  __syncthreads();

  for (int n = 0; n < NSTEPS; ++n) {
    const float* __restrict__ Wih0n = Wih0 + (size_t)n * G3H * 2;
    const float* __restrict__ Whh0n = Whh0 + (size_t)n * G3H * HDIM;
    const float* __restrict__ bih0n = bih0 + (size_t)n * G3H;
    const float* __restrict__ bhh0n = bhh0 + (size_t)n * G3H;
    const float* __restrict__ Wih1n = Wih1 + (size_t)n * G3H * HDIM;
    const float* __restrict__ Whh1n = Whh1 + (size_t)n * G3H * HDIM;
    const float* __restrict__ bih1n = bih1 + (size_t)n * G3H;
    const float* __restrict__ bhh1n = bhh1 + (size_t)n * G3H;
    const float* __restrict__ W1n = W1 + (size_t)n * HDIM * HDIM;
    const float* __restrict__ b1n = b1 + (size_t)n * HDIM;
    const float* __restrict__ W2n = W2 + (size_t)n * 2 * HDIM;
    const float* __restrict__ b2n = b2 + (size_t)n * 2;

    {
      float acc[6][4];
#pragma unroll
      for (int g = 0; g < 6; ++g) {
        const float bias = bhh0n[tj + g * 64];
#pragma unroll
        for (int i = 0; i < 4; ++i) acc[g][i] = bias;
      }
      for (int kk = 0; kk < HDIM; kk += 16) {
#pragma unroll
        for (int s = 0; s < 4; ++s) {
          const int k = kk + s * 4;
          float4 w[6];
#pragma unroll
          for (int g = 0; g < 6; ++g)
            w[g] = *(const float4*)(Whh0n + (size_t)(tj + g * 64) * HDIM + k);
#pragma unroll
          for (int i = 0; i < 4; ++i) {
            const float4 hv = *(const float4*)&h1[tq + 4 * i][k];
#pragma unroll
            for (int g = 0; g < 6; ++g) acc[g][i] = dot4(w[g], hv, acc[g][i]);
          }
        }
      }
#pragma unroll
      for (int g = 0; g < 6; ++g)
#pragma unroll
        for (int i = 0; i < 4; ++i) S[tq + 4 * i][tj + g * 64] = acc[g][i];
    }
    __syncthreads();

#pragma unroll
    for (int rep = 0; rep < (BT * HDIM) / THREADS; ++rep) {
      const int idx = tid + rep * THREADS;
      const int b = idx >> 7;
      const int d = idx & 127;
      const float x0 = xin[b][0];
      const float x1 = xin[b][1];
      const float gir = fmaf(Wih0n[d * 2 + 0], x0, fmaf(Wih0n[d * 2 + 1], x1, bih0n[d]));
      const float giz = fmaf(Wih0n[(d + 128) * 2 + 0], x0,
                             fmaf(Wih0n[(d + 128) * 2 + 1], x1, bih0n[d + 128]));
      const float gin = fmaf(Wih0n[(d + 256) * 2 + 0], x0,
                             fmaf(Wih0n[(d + 256) * 2 + 1], x1, bih0n[d + 256]));
      const float r = sigmoidf(gir + S[b][d]);
      const float z = sigmoidf(giz + S[b][d + 128]);
      const float nn = tanhf(gin + r * S[b][d + 256]);
      h1[b][d] = (1.0f - z) * nn + z * h1[b][d];
    }
    __syncthreads();

    {
      float acc[6][4];
#pragma unroll
      for (int g = 0; g < 6; ++g) {
        const float bias = bhh1n[tj + g * 64];
#pragma unroll
        for (int i = 0; i < 4; ++i) acc[g][i] = bias;
      }
      for (int kk = 0; kk < HDIM; kk += 16) {
#pragma unroll
        for (int s = 0; s < 4; ++s) {
          const int k = kk + s * 4;
          float4 w[6];
#pragma unroll
          for (int g = 0; g < 6; ++g)
            w[g] = *(const float4*)(Whh1n + (size_t)(tj + g * 64) * HDIM + k);
#pragma unroll
          for (int i = 0; i < 4; ++i) {
            const float4 hv = *(const float4*)&h2[tq + 4 * i][k];
#pragma unroll
            for (int g = 0; g < 6; ++g) acc[g][i] = dot4(w[g], hv, acc[g][i]);
          }
        }
      }
#pragma unroll
      for (int g = 0; g < 6; ++g)
#pragma unroll
        for (int i = 0; i < 4; ++i) S[tq + 4 * i][tj + g * 64] = acc[g][i];
    }

    {
      float acc[6][4];
#pragma unroll
      for (int g = 0; g < 6; ++g) {
        const float bias = bih1n[tj + g * 64];
#pragma unroll
        for (int i = 0; i < 4; ++i) acc[g][i] = bias;
      }
      for (int kk = 0; kk < HDIM; kk += 16) {
#pragma unroll
        for (int s = 0; s < 4; ++s) {
          const int k = kk + s * 4;
          float4 w[6];
#pragma unroll
          for (int g = 0; g < 6; ++g)
            w[g] = *(const float4*)(Wih1n + (size_t)(tj + g * 64) * HDIM + k);
#pragma unroll
          for (int i = 0; i < 4; ++i) {
            const float4 hv = *(const float4*)&h1[tq + 4 * i][k];
#pragma unroll
            for (int g = 0; g < 6; ++g) acc[g][i] = dot4(w[g], hv, acc[g][i]);
          }
        }
      }
#pragma unroll
      for (int g = 0; g < 6; ++g) {
        const int row = tj + g * 64;
#pragma unroll
        for (int i = 0; i < 4; ++i) {
          if (row < 256) S[tq + 4 * i][row] += acc[g][i];
          else           S[tq + 4 * i][row + 128] = acc[g][i];
        }
      }
    }
    __syncthreads();

#pragma unroll
    for (int rep = 0; rep < (BT * HDIM) / THREADS; ++rep) {
      const int idx = tid + rep * THREADS;
      const int b = idx >> 7;
      const int d = idx & 127;
      const float r = sigmoidf(S[b][d]);
      const float z = sigmoidf(S[b][d + 128]);
      const float nn = tanhf(S[b][d + 384] + r * S[b][d + 256]);
      const float h2n = (1.0f - z) * nn + z * h2[b][d];
      h2[b][d] = h2n;
      S[b][d] = cosf(h2n) + 1e-10f;
    }
    __syncthreads();

    {
      float acc[2][4];
#pragma unroll
      for (int g = 0; g < 2; ++g) {
        const float bias = b1n[tj + g * 64];
#pragma unroll
        for (int i = 0; i < 4; ++i) acc[g][i] = bias;
      }
      for (int kk = 0; kk < HDIM; kk += 16) {
#pragma unroll
        for (int s = 0; s < 4; ++s) {
          const int k = kk + s * 4;
          float4 w[2];
          w[0] = *(const float4*)(W1n + (size_t)(tj)*HDIM + k);
          w[1] = *(const float4*)(W1n + (size_t)(tj + 64) * HDIM + k);
#pragma unroll
          for (int i = 0; i < 4; ++i) {
            const float4 sv = *(const float4*)&S[tq + 4 * i][k];
            acc[0][i] = dot4(w[0], sv, acc[0][i]);
            acc[1][i] = dot4(w[1], sv, acc[1][i]);
          }
        }
      }
#pragma unroll
      for (int g = 0; g < 2; ++g)
#pragma unroll
        for (int i = 0; i < 4; ++i)
          S[tq + 4 * i][384 + tj + g * 64] = fmaxf(acc[g][i], 0.0f);
    }
    __syncthreads();

    {
      const int ln = tid & 15;
      const int b = tid >> 4;
      const int kb = ln * 8;
      float a0 = 0.0f, a1 = 0.0f;
#pragma unroll
      for (int k = 0; k < 8; ++k) {
        const float hd = S[b][384 + kb + k];
        a0 = fmaf(W2n[kb + k], hd, a0);
        a1 = fmaf(W2n[HDIM + kb + k], hd, a1);
      }
#pragma unroll
      for (int off = 8; off >= 1; off >>= 1) {
        a0 += __shfl_xor(a0, off, 16);
        a1 += __shfl_xor(a1, off, 16);
      }
      if (ln == 0) {
        const float l0 = a0 + b2n[0];
        const float l1 = a1 + b2n[1];
        const float m = fmaxf(l0, l1);
        const float e0 = expf(l0 - m);
        const float e1 = expf(l1 - m);
        const float sum = e0 + e1;
        const float p0 = e0 / sum + 1e-10f;
        const float p1 = e1 / sum + 1e-10f;
        const int gb = b0 + b;
        out[((size_t)gb * NSTEPS + n) * 2 + 0] = p0;
        out[((size_t)gb * NSTEPS + n) * 2 + 1] = p1;

        uint32_t k0n, k1n;
        tf2x32(0u, 42u, 0u, (uint32_t)n, k0n, k1n);
        uint32_t o0, o1;
        tf2x32(k0n, k1n, 0u, (uint32_t)(2 * gb), o0, o1);
        const float u0 = u01_from_bits(o0 ^ o1);
        tf2x32(k0n, k1n, 0u, (uint32_t)(2 * gb + 1), o0, o1);
        const float u1 = u01_from_bits(o0 ^ o1);
        const float g0 = -logf(-logf(u0));
        const float g1 = -logf(-logf(u1));
        const float z0 = logf(p0) + g0;
        const float z1 = logf(p1) + g1;
        const int smp = (z1 > z0) ? 1 : 0;
        xin[b][0] = (smp == 0) ? 1.0f : 0.0f;
        xin[b][1] = (smp == 1) ? 1.0f : 0.0f;
      }
    }
    __syncthreads();
  }
}

extern "C" void kernel_launch(void* const* d_in, const int* in_sizes, int n_in,
                              void* d_out, int out_size, void* d_ws, size_t ws_size,
                              hipStream_t stream) {
  (void)in_sizes; (void)n_in; (void)out_size;
  const float* inputs = (const float*)d_in[0];
  const float* Wih0 = (const float*)d_in[1];
  const float* Whh0 = (const float*)d_in[2];
  const float* bih0 = (const float*)d_in[3];
  const float* bhh0 = (const float*)d_in[4];
  const float* Wih1 = (const float*)d_in[5];
  const float* Whh1 = (const float*)d_in[6];
  const float* bih1 = (const float*)d_in[7];
  const float* bhh1 = (const float*)d_in[8];
  const float* W1 = (const float*)d_in[9];
  const float* b1 = (const float*)d_in[10];
  const float* W2 = (const float*)d_in[11];
  const float* b2 = (const float*)d_in[12];
  float* out = (float*)d_out;

  // ws layout: 6 big frag arrays (Whh0/Wih1/Whh1 x hi/lo) of 6,291,456 f16
  // elems each, then 2 W1 arrays of 2,097,152 elems each. Total 80 MiB.
  constexpr size_t EB = 6291456;        // 128*24*4*64*8
  constexpr size_t EW1 = 2097152;       // 128*8*4*64*8
  constexpr size_t WS_NEEDED = (6 * EB + 2 * EW1) * sizeof(_Float16);  // 83,886,080

  if (ws_size >= WS_NEEDED) {
    _Float16* w = (_Float16*)d_ws;
    _Float16* Whh0_1 = w;
    _Float16* Whh0_2 = w + EB;
    _Float16* Wih1_1 = w + 2 * EB;
    _Float16* Wih1_2 = w + 3 * EB;
    _Float16* Whh1_1 = w + 4 * EB;
    _Float16* Whh1_2 = w + 5 * EB;
    _Float16* W1_1 = w + 6 * EB;
    _Float16* W1_2 = w + 6 * EB + EW1;

    hipLaunchKernelGGL(preprocess_split_kernel, dim3(3072), dim3(256), 0, stream,
                       Whh0, Whh0_1, Whh0_2, 786432, 24);
    hipLaunchKernelGGL(preprocess_split_kernel, dim3(3072), dim3(256), 0, stream,
                       Wih1, Wih1_1, Wih1_2, 786432, 24);
    hipLaunchKernelGGL(preprocess_split_kernel, dim3(3072), dim3(256), 0, stream,
                       Whh1, Whh1_1, Whh1_2, 786432, 24);
    hipLaunchKernelGGL(preprocess_split_kernel, dim3(1024), dim3(256), 0, stream,
                       W1, W1_1, W1_2, 262144, 8);
    hipLaunchKernelGGL(rnn_wavefn_mfma_kernel, dim3(8192 / BT), dim3(THREADS), 0, stream,
                       inputs, Wih0, bih0, bhh0, bih1, bhh1, b1, W2, b2,
                       Whh0_1, Whh0_2, Wih1_1, Wih1_2, Whh1_1, Whh1_2, W1_1, W1_2,
                       out);
  } else {
    hipLaunchKernelGGL(rnn_wavefn_fp32_kernel, dim3(8192 / BT), dim3(THREADS), 0, stream,
                       inputs, Wih0, Whh0, bih0, bhh0, Wih1, Whh1, bih1, bhh1,
                       W1, b1, W2, b2, out);
  }
}

// Round 5
// 3326.522 us; speedup vs baseline: 4.3754x; 1.3173x over previous
//
#include <hip/hip_runtime.h>
#include <cstdint>

// binary_disordered_RNNwavefunction: 128-step 2-layer GRU + MLP + softmax +
// threefry categorical sampling, B=8192, H=128, I=2.
//
// R5: BT 32, one 512-thread block per CU (grid 256). Each B fragment feeds
// TWO 16-row m-tiles -> B-load instructions and L2->CU traffic halve vs R4
// (R4 accounting: loads ~2.9M cyc/CU were dominant; MFMA only 1.19M = the
// measured 9.8% MfmaUtil). h1/h2 fp32 state lives in per-thread registers
// (fixed (b,d) ownership across steps). S stride 513 (== 1 mod 32) keeps the
// b=lane&31 combine mapping LDS-conflict-free.
//
// Numerics (verified R4, absmax 0.0039 = no sample flips): split-f16
// a = a1 + a2s/4096; 3 MFMAs per tile (A1B1; A1B2s+A2sB1 into x4096-scaled
// acc); dropped A2sB2s ~3e-8. RNG: modern JAX threefry_partitionable.
// R2 lesson: keep blocks few + synced for L2 reuse (here: 256 blocks).

namespace {

constexpr int NSTEPS = 128;
constexpr int HDIM = 128;
constexpr int G3H = 384;

// MFMA kernel config
constexpr int BTM = 32;        // batch rows per block
constexpr int THM = 512;       // threads (8 waves)
constexpr int SPM = 513;       // S row stride, ==1 mod 32 -> combine conflict-free

// fallback (R3) config
constexpr int BT = 16;
constexpr int THREADS = 256;
constexpr int HP = 132;
constexpr int SP = 516;

typedef _Float16 half8 __attribute__((ext_vector_type(8)));
typedef float f32x4 __attribute__((ext_vector_type(4)));

constexpr float LO_SCALE = 4096.0f;
constexpr float LO_INV = 2.44140625e-4f;   // 1/4096
constexpr float F16_MIN_NORM = 6.104e-5f;

__device__ __forceinline__ void split_f16(float x, _Float16& a1, _Float16& a2s) {
  _Float16 h = (fabsf(x) < F16_MIN_NORM) ? (_Float16)0.0f : (_Float16)x;
  a1 = h;
  a2s = (_Float16)((x - (float)h) * LO_SCALE);
}

__device__ __forceinline__ void tf2x32(uint32_t k0, uint32_t k1,
                                       uint32_t x0, uint32_t x1,
                                       uint32_t& o0, uint32_t& o1) {
  const uint32_t ks2 = k0 ^ k1 ^ 0x1BD11BDAu;
  uint32_t v0 = x0 + k0;
  uint32_t v1 = x1 + k1;
  const uint32_t ks[3] = {k0, k1, ks2};
  const uint32_t rotA[4] = {13u, 15u, 26u, 6u};
  const uint32_t rotB[4] = {17u, 29u, 16u, 24u};
#pragma unroll
  for (int i = 0; i < 5; ++i) {
#pragma unroll
    for (int j = 0; j < 4; ++j) {
      const uint32_t r = (i & 1) ? rotB[j] : rotA[j];
      v0 += v1;
      v1 = (v1 << r) | (v1 >> (32u - r));
      v1 ^= v0;
    }
    v0 += ks[(i + 1) % 3];
    v1 += ks[(i + 2) % 3] + (uint32_t)(i + 1);
  }
  o0 = v0;
  o1 = v1;
}

__device__ __forceinline__ float u01_from_bits(uint32_t bits) {
  const float tiny = 1.1754943508222875e-38f;
  float f = __uint_as_float((bits >> 9) | 0x3F800000u) - 1.0f;
  float u = f * (1.0f - tiny) + tiny;
  return fmaxf(tiny, u);
}

__device__ __forceinline__ float sigmoidf(float x) {
  return 1.0f / (1.0f + expf(-x));
}

__device__ __forceinline__ float dot4(const float4 a, const float4 b, float c) {
  c = fmaf(a.x, b.x, c);
  c = fmaf(a.y, b.y, c);
  c = fmaf(a.z, b.z, c);
  c = fmaf(a.w, b.w, c);
  return c;
}

__device__ __forceinline__ void load_Afrag(const _Float16* arr, int lane,
                                           half8 (&A)[2][4]) {
#pragma unroll
  for (int mt = 0; mt < 2; ++mt)
#pragma unroll
    for (int kt = 0; kt < 4; ++kt)
      A[mt][kt] = *(const half8*)(arr + mt * 2048 + (kt * 64 + lane) * 8);
}

// One jt tile: 8 B-loads, 24 MFMAs (2 m-tiles x 4 kt x 3 split-terms).
__device__ __forceinline__ void mfma_tile(const half8 (&A1)[2][4],
                                          const half8 (&A2)[2][4],
                                          const _Float16* __restrict__ B1,
                                          const _Float16* __restrict__ B2,
                                          int jt, int lane,
                                          f32x4 (&c1)[2], f32x4 (&c2)[2]) {
#pragma unroll
  for (int kt = 0; kt < 4; ++kt) {
    const size_t o = ((size_t)(jt * 4 + kt) * 64 + lane) * 8;
    const half8 b1v = *(const half8*)(B1 + o);
    const half8 b2v = *(const half8*)(B2 + o);
#pragma unroll
    for (int mt = 0; mt < 2; ++mt) {
      c1[mt] = __builtin_amdgcn_mfma_f32_16x16x32_f16(A1[mt][kt], b1v, c1[mt], 0, 0, 0);
      c2[mt] = __builtin_amdgcn_mfma_f32_16x16x32_f16(A1[mt][kt], b2v, c2[mt], 0, 0, 0);
      c2[mt] = __builtin_amdgcn_mfma_f32_16x16x32_f16(A2[mt][kt], b1v, c2[mt], 0, 0, 0);
    }
  }
}

}  // namespace

// ---------------------------------------------------------------------------
// Preprocess: fp32 W[n][JT*16][128] -> frag-layout split-f16 arrays (as R4)
// ---------------------------------------------------------------------------
extern "C" __global__ __launch_bounds__(256)
void preprocess_split_kernel(const float* __restrict__ src,
                             _Float16* __restrict__ d1,
                             _Float16* __restrict__ d2,
                             int total, int JT) {
  const int idx = blockIdx.x * 256 + threadIdx.x;
  if (idx >= total) return;
  const int lane = idx & 63;
  const int kt = (idx >> 6) & 3;
  const int rest = idx >> 8;
  const int jt = rest % JT;
  const int nstep = rest / JT;

  const int j = jt * 16 + (lane & 15);
  const int k0 = kt * 32 + ((lane >> 4) << 3);
  const float* p = src + ((size_t)nstep * (JT * 16) + j) * 128 + k0;
  const float4 w0 = *(const float4*)p;
  const float4 w1 = *(const float4*)(p + 4);
  const float xs[8] = {w0.x, w0.y, w0.z, w0.w, w1.x, w1.y, w1.z, w1.w};

  half8 o1, o2;
#pragma unroll
  for (int t = 0; t < 8; ++t) {
    _Float16 a1, a2s;
    split_f16(xs[t], a1, a2s);
    o1[t] = a1;
    o2[t] = a2s;
  }
  *(half8*)(d1 + (size_t)idx * 8) = o1;
  *(half8*)(d2 + (size_t)idx * 8) = o2;
}

// ---------------------------------------------------------------------------
// Main MFMA kernel: BT=32, 512 threads, 1 block/CU
// ---------------------------------------------------------------------------
extern "C" __global__ __launch_bounds__(512, 2)
void rnn_wavefn_mfma_kernel(const float* __restrict__ inputs,
                            const float* __restrict__ Wih0,
                            const float* __restrict__ bih0,
                            const float* __restrict__ bhh0,
                            const float* __restrict__ bih1,
                            const float* __restrict__ bhh1,
                            const float* __restrict__ b1,
                            const float* __restrict__ W2,
                            const float* __restrict__ b2,
                            const _Float16* __restrict__ Whh0_1,
                            const _Float16* __restrict__ Whh0_2,
                            const _Float16* __restrict__ Wih1_1,
                            const _Float16* __restrict__ Wih1_2,
                            const _Float16* __restrict__ Whh1_1,
                            const _Float16* __restrict__ Whh1_2,
                            const _Float16* __restrict__ W1_1,
                            const _Float16* __restrict__ W1_2,
                            float* __restrict__ out) {
  __shared__ float S[BTM][SPM];                 // 65,664 B
  __shared__ _Float16 h1A1[4096], h1A2[4096];   // [mt*2048 + (kt*64+lane)*8+j]
  __shared__ _Float16 h2A1[4096], h2A2[4096];
  __shared__ _Float16 csA1[4096], csA2[4096];   // 6*8KB = 49,152 B
  __shared__ float xin[BTM][2];

  const int tid = threadIdx.x;
  const int b0 = blockIdx.x * BTM;
  const int wv = tid >> 6;        // 0..7
  const int lane = tid & 63;
  const int lm = lane & 15;
  const int m0 = (lane >> 4) * 4;

  // combine-phase fixed ownership: b = tid&31, d = (tid>>5) + rep*16
  const int cb = tid & 31;
  const int ct5 = tid >> 5;
  const int cmt = cb >> 4;
  const int cbm = cb & 15;

  float h1r[8], h2r[8];
#pragma unroll
  for (int i = 0; i < 8; ++i) { h1r[i] = 0.0f; h2r[i] = 0.0f; }
  for (int i = tid; i < 4096; i += THM) {
    h1A1[i] = (_Float16)0.0f; h1A2[i] = (_Float16)0.0f;
    h2A1[i] = (_Float16)0.0f; h2A2[i] = (_Float16)0.0f;
  }
  if (tid < BTM * 2) {
    xin[tid >> 1][tid & 1] = inputs[(b0 + (tid >> 1)) * 2 + (tid & 1)];
  }
  __syncthreads();

  for (int n = 0; n < NSTEPS; ++n) {
    const float* __restrict__ Wih0n = Wih0 + (size_t)n * G3H * 2;
    const float* __restrict__ bih0n = bih0 + (size_t)n * G3H;
    const float* __restrict__ bhh0n = bhh0 + (size_t)n * G3H;
    const float* __restrict__ bih1n = bih1 + (size_t)n * G3H;
    const float* __restrict__ bhh1n = bhh1 + (size_t)n * G3H;
    const float* __restrict__ b1n = b1 + (size_t)n * HDIM;
    const float* __restrict__ W2n = W2 + (size_t)n * 2 * HDIM;
    const float* __restrict__ b2n = b2 + (size_t)n * 2;
    const size_t fo3 = (size_t)n * 49152;
    const size_t fo1 = (size_t)n * 16384;

    // ---------- GH0: S[b][j] = bhh0[j] + Whh0[j,:].h1[b,:]
    {
      half8 A1[2][4], A2[2][4];
      load_Afrag(h1A1, lane, A1);
      load_Afrag(h1A2, lane, A2);
      const _Float16* B1 = Whh0_1 + fo3;
      const _Float16* B2 = Whh0_2 + fo3;
#pragma unroll
      for (int t = 0; t < 3; ++t) {
        const int jt = wv * 3 + t;
        f32x4 c1[2] = {{0.f,0.f,0.f,0.f},{0.f,0.f,0.f,0.f}};
        f32x4 c2[2] = {{0.f,0.f,0.f,0.f},{0.f,0.f,0.f,0.f}};
        mfma_tile(A1, A2, B1, B2, jt, lane, c1, c2);
        const int col = jt * 16 + lm;
        const float bias = bhh0n[col];
#pragma unroll
        for (int mt = 0; mt < 2; ++mt)
#pragma unroll
          for (int r = 0; r < 4; ++r)
            S[mt * 16 + m0 + r][col] = bias + fmaf(c2[mt][r], LO_INV, c1[mt][r]);
      }
    }
    __syncthreads();

    // ---------- C0: GRU0 combine -> h1 (registers) + split A-layout
    {
      const float x0 = xin[cb][0];
      const float x1 = xin[cb][1];
#pragma unroll
      for (int rep = 0; rep < 8; ++rep) {
        const int d = ct5 + rep * 16;
        const float gir = fmaf(Wih0n[d * 2 + 0], x0, fmaf(Wih0n[d * 2 + 1], x1, bih0n[d]));
        const float giz = fmaf(Wih0n[(d + 128) * 2 + 0], x0,
                               fmaf(Wih0n[(d + 128) * 2 + 1], x1, bih0n[d + 128]));
        const float gin = fmaf(Wih0n[(d + 256) * 2 + 0], x0,
                               fmaf(Wih0n[(d + 256) * 2 + 1], x1, bih0n[d + 256]));
        const float r = sigmoidf(gir + S[cb][d]);
        const float z = sigmoidf(giz + S[cb][d + 128]);
        const float nn = tanhf(gin + r * S[cb][d + 256]);
        const float h1n = (1.0f - z) * nn + z * h1r[rep];
        h1r[rep] = h1n;
        const int si = cmt * 2048 +
            (((d >> 5) << 6) + (((d >> 3) & 3) << 4) + cbm) * 8 + (d & 7);
        _Float16 a1, a2s;
        split_f16(h1n, a1, a2s);
        h1A1[si] = a1;
        h1A2[si] = a2s;
      }
    }
    __syncthreads();

    // ---------- GH1a: S = bhh1 + Whh1.h2 (all 24 jt)
    {
      half8 A1[2][4], A2[2][4];
      load_Afrag(h2A1, lane, A1);
      load_Afrag(h2A2, lane, A2);
      const _Float16* B1 = Whh1_1 + fo3;
      const _Float16* B2 = Whh1_2 + fo3;
#pragma unroll
      for (int t = 0; t < 3; ++t) {
        const int jt = wv * 3 + t;
        f32x4 c1[2] = {{0.f,0.f,0.f,0.f},{0.f,0.f,0.f,0.f}};
        f32x4 c2[2] = {{0.f,0.f,0.f,0.f},{0.f,0.f,0.f,0.f}};
        mfma_tile(A1, A2, B1, B2, jt, lane, c1, c2);
        const int col = jt * 16 + lm;
        const float bias = bhh1n[col];
#pragma unroll
        for (int mt = 0; mt < 2; ++mt)
#pragma unroll
          for (int r = 0; r < 4; ++r)
            S[mt * 16 + m0 + r][col] = bias + fmaf(c2[mt][r], LO_INV, c1[mt][r]);
      }
    }
    // no barrier: GH1b touches identical (thread -> S slot) ownership

    // ---------- GH1b: gi1 = bih1 + Wih1.h1new; r,z summed; n kept separate
    {
      half8 A1[2][4], A2[2][4];
      load_Afrag(h1A1, lane, A1);
      load_Afrag(h1A2, lane, A2);
      const _Float16* B1 = Wih1_1 + fo3;
      const _Float16* B2 = Wih1_2 + fo3;
#pragma unroll
      for (int t = 0; t < 3; ++t) {
        const int jt = wv * 3 + t;
        f32x4 c1[2] = {{0.f,0.f,0.f,0.f},{0.f,0.f,0.f,0.f}};
        f32x4 c2[2] = {{0.f,0.f,0.f,0.f},{0.f,0.f,0.f,0.f}};
        mfma_tile(A1, A2, B1, B2, jt, lane, c1, c2);
        const int col = jt * 16 + lm;
        const float bias = bih1n[col];
        if (jt < 16) {   // r,z: accumulate gi+gh
#pragma unroll
          for (int mt = 0; mt < 2; ++mt)
#pragma unroll
            for (int r = 0; r < 4; ++r)
              S[mt * 16 + m0 + r][col] += bias + fmaf(c2[mt][r], LO_INV, c1[mt][r]);
        } else {         // n: gi_n separate at col+128 (slots 384..511)
#pragma unroll
          for (int mt = 0; mt < 2; ++mt)
#pragma unroll
            for (int r = 0; r < 4; ++r)
              S[mt * 16 + m0 + r][col + 128] = bias + fmaf(c2[mt][r], LO_INV, c1[mt][r]);
        }
      }
    }
    __syncthreads();

    // ---------- C1: GRU1 combine -> h2 (registers); cos -> split A-layout
    {
#pragma unroll
      for (int rep = 0; rep < 8; ++rep) {
        const int d = ct5 + rep * 16;
        const float r = sigmoidf(S[cb][d]);
        const float z = sigmoidf(S[cb][d + 128]);
        const float nn = tanhf(S[cb][d + 384] + r * S[cb][d + 256]);
        const float h2n = (1.0f - z) * nn + z * h2r[rep];
        h2r[rep] = h2n;
        const int si = cmt * 2048 +
            (((d >> 5) << 6) + (((d >> 3) & 3) << 4) + cbm) * 8 + (d & 7);
        _Float16 a1, a2s;
        split_f16(h2n, a1, a2s);
        h2A1[si] = a1;
        h2A2[si] = a2s;
        const float cv = cosf(h2n) + 1e-10f;
        split_f16(cv, a1, a2s);
        csA1[si] = a1;
        csA2[si] = a2s;
      }
    }
    __syncthreads();

    // ---------- HDN: S[b][384+d] = relu(b1[d] + W1[d,:].cos[b,:])
    {
      half8 A1[2][4], A2[2][4];
      load_Afrag(csA1, lane, A1);
      load_Afrag(csA2, lane, A2);
      const int jt = wv;   // 8 waves, 8 jt tiles
      f32x4 c1[2] = {{0.f,0.f,0.f,0.f},{0.f,0.f,0.f,0.f}};
      f32x4 c2[2] = {{0.f,0.f,0.f,0.f},{0.f,0.f,0.f,0.f}};
      mfma_tile(A1, A2, W1_1 + fo1, W1_2 + fo1, jt, lane, c1, c2);
      const int col = jt * 16 + lm;
      const float bias = b1n[col];
#pragma unroll
      for (int mt = 0; mt < 2; ++mt)
#pragma unroll
        for (int r = 0; r < 4; ++r)
          S[mt * 16 + m0 + r][384 + col] =
              fmaxf(bias + fmaf(c2[mt][r], LO_INV, c1[mt][r]), 0.0f);
    }
    __syncthreads();

    // ---------- OUT: logits, softmax+1e-10, store p, threefry-gumbel sample
    {
      const int ln = tid & 15;
      const int ob = tid >> 4;    // 0..31
      const int kb = ln * 8;
      float a0 = 0.0f, a1 = 0.0f;
#pragma unroll
      for (int k = 0; k < 8; ++k) {
        const float hd = S[ob][384 + kb + k];
        a0 = fmaf(W2n[kb + k], hd, a0);
        a1 = fmaf(W2n[HDIM + kb + k], hd, a1);
      }
#pragma unroll
      for (int off = 8; off >= 1; off >>= 1) {
        a0 += __shfl_xor(a0, off, 16);
        a1 += __shfl_xor(a1, off, 16);
      }
      if (ln == 0) {
        const float l0 = a0 + b2n[0];
        const float l1 = a1 + b2n[1];
        const float m = fmaxf(l0, l1);
        const float e0 = expf(l0 - m);
        const float e1 = expf(l1 - m);
        const float sum = e0 + e1;
        const float p0 = e0 / sum + 1e-10f;
        const float p1 = e1 / sum + 1e-10f;
        const int gb = b0 + ob;
        out[((size_t)gb * NSTEPS + n) * 2 + 0] = p0;
        out[((size_t)gb * NSTEPS + n) * 2 + 1] = p1;

        uint32_t k0n, k1n;
        tf2x32(0u, 42u, 0u, (uint32_t)n, k0n, k1n);
        uint32_t o0, o1;
        tf2x32(k0n, k1n, 0u, (uint32_t)(2 * gb), o0, o1);
        const float u0 = u01_from_bits(o0 ^ o1);
        tf2x32(k0n, k1n, 0u, (uint32_t)(2 * gb + 1), o0, o1);
        const float u1 = u01_from_bits(o0 ^ o1);
        const float g0 = -logf(-logf(u0));
        const float g1 = -logf(-logf(u1));
        const float z0 = logf(p0) + g0;
        const float z1 = logf(p1) + g1;
        const int smp = (z1 > z0) ? 1 : 0;
        xin[ob][0] = (smp == 0) ? 1.0f : 0.0f;
        xin[ob][1] = (smp == 1) ? 1.0f : 0.0f;
      }
    }
    __syncthreads();
  }
}

// ---------------------------------------------------------------------------
// Fallback: R3 fp32-VALU kernel (proven, 7.2 ms) — used if ws too small.
// ---------------------------------------------------------------------------
extern "C" __global__ __launch_bounds__(256, 2)
void rnn_wavefn_fp32_kernel(const float* __restrict__ inputs,
                            const float* __restrict__ Wih0,
                            const float* __restrict__ Whh0,
                            const float* __restrict__ bih0,
                            const float* __restrict__ bhh0,
                            const float* __restrict__ Wih1,
                            const float* __restrict__ Whh1,
                            const float* __restrict__ bih1,
                            const float* __restrict__ bhh1,
                            const float* __restrict__ W1,
                            const float* __restrict__ b1,
                            const float* __restrict__ W2,
                            const float* __restrict__ b2,
                            float* __restrict__ out) {
  __shared__ float h1[BT][HP];
  __shared__ float h2[BT][HP];
  __shared__ float S[BT][SP];
  __shared__ float xin[BT][2];

  const int tid = threadIdx.x;
  const int b0 = blockIdx.x * BT;
  const int tj = tid >> 2;
  const int tq = tid & 3;

  for (int i = tid; i < BT * HP; i += THREADS) {
    ((float*)h1)[i] = 0.0f;
    ((float*)h2)[i] = 0.0f;
  }
  if (tid < BT * 2) {
    xin[tid >> 1][tid & 1] = inputs[(b0 + (tid >> 1)) * 2 + (tid & 1)];
  }
  __syncthreads();

  for (int n = 0; n < NSTEPS; ++n) {
    const float* __restrict__ Wih0n = Wih0 + (size_t)n * G3H * 2;
    const float* __restrict__ Whh0n = Whh0 + (size_t)n * G3H * HDIM;
    const float* __restrict__ bih0n = bih0 + (size_t)n * G3H;
    const float* __restrict__ bhh0n = bhh0 + (size_t)n * G3H;
    const float* __restrict__ Wih1n = Wih1 + (size_t)n * G3H * HDIM;
    const float* __restrict__ Whh1n = Whh1 + (size_t)n * G3H * HDIM;
    const float* __restrict__ bih1n = bih1 + (size_t)n * G3H;
    const float* __restrict__ bhh1n = bhh1 + (size_t)n * G3H;
    const float* __restrict__ W1n = W1 + (size_t)n * HDIM * HDIM;
    const float* __restrict__ b1n = b1 + (size_t)n * HDIM;
    const float* __restrict__ W2n = W2 + (size_t)n * 2 * HDIM;
    const float* __restrict__ b2n = b2 + (size_t)n * 2;

    {
      float acc[6][4];
#pragma unroll
      for (int g = 0; g < 6; ++g) {
        const float bias = bhh0n[tj + g * 64];
#pragma unroll
        for (int i = 0; i < 4; ++i) acc[g][i] = bias;
      }
      for (int kk = 0; kk < HDIM; kk += 16) {
#pragma unroll
        for (int s = 0; s < 4; ++s) {
          const int k = kk + s * 4;
          float4 w[6];
#pragma unroll
          for (int g = 0; g < 6; ++g)
            w[g] = *(const float4*)(Whh0n + (size_t)(tj + g * 64) * HDIM + k);
#pragma unroll
          for (int i = 0; i < 4; ++i) {
            const float4 hv = *(const float4*)&h1[tq + 4 * i][k];
#pragma unroll
            for (int g = 0; g < 6; ++g) acc[g][i] = dot4(w[g], hv, acc[g][i]);
          }
        }
      }
#pragma unroll
      for (int g = 0; g < 6; ++g)
#pragma unroll
        for (int i = 0; i < 4; ++i) S[tq + 4 * i][tj + g * 64] = acc[g][i];
    }
    __syncthreads();

#pragma unroll
    for (int rep = 0; rep < (BT * HDIM) / THREADS; ++rep) {
      const int idx = tid + rep * THREADS;
      const int b = idx >> 7;
      const int d = idx & 127;
      const float x0 = xin[b][0];
      const float x1 = xin[b][1];
      const float gir = fmaf(Wih0n[d * 2 + 0], x0, fmaf(Wih0n[d * 2 + 1], x1, bih0n[d]));
      const float giz = fmaf(Wih0n[(d + 128) * 2 + 0], x0,
                             fmaf(Wih0n[(d + 128) * 2 + 1], x1, bih0n[d + 128]));
      const float gin = fmaf(Wih0n[(d + 256) * 2 + 0], x0,
                             fmaf(Wih0n[(d + 256) * 2 + 1], x1, bih0n[d + 256]));
      const float r = sigmoidf(gir + S[b][d]);
      const float z = sigmoidf(giz + S[b][d + 128]);
      const float nn = tanhf(gin + r * S[b][d + 256]);
      h1[b][d] = (1.0f - z) * nn + z * h1[b][d];
    }
    __syncthreads();

    {
      float acc[6][4];
#pragma unroll
      for (int g = 0; g < 6; ++g) {
        const float bias = bhh1n[tj + g * 64];
#pragma unroll
        for (int i = 0; i < 4; ++i) acc[g][i] = bias;
      }
      for (int kk = 0; kk < HDIM; kk += 16) {
#pragma unroll
        for (int s = 0; s < 4; ++s) {
          const int k = kk + s * 4;
          float4 w[6];
#pragma unroll
          for (int g = 0; g < 6; ++g)
            w[g] = *(const float4*)(Whh1n + (size_t)(tj + g * 64) * HDIM + k);
#pragma unroll
          for (int i = 0; i < 4; ++i) {
            const float4 hv = *(const float4*)&h2[tq + 4 * i][k];
#pragma unroll
            for (int g = 0; g < 6; ++g) acc[g][i] = dot4(w[g], hv, acc[g][i]);
          }
        }
      }
#pragma unroll
      for (int g = 0; g < 6; ++g)
#pragma unroll
        for (int i = 0; i < 4; ++i) S[tq + 4 * i][tj + g * 64] = acc[g][i];
    }

    {
      float acc[6][4];
#pragma unroll
      for (int g = 0; g < 6; ++g) {
        const float bias = bih1n[tj + g * 64];
#pragma unroll
        for (int i = 0; i < 4; ++i) acc[g][i] = bias;
      }
      for (int kk = 0; kk < HDIM; kk += 16) {
#pragma unroll
        for (int s = 0; s < 4; ++s) {
          const int k = kk + s * 4;
          float4 w[6];
#pragma unroll
          for (int g = 0; g < 6; ++g)
            w[g] = *(const float4*)(Wih1n + (size_t)(tj + g * 64) * HDIM + k);
#pragma unroll
          for (int i = 0; i < 4; ++i) {
            const float4 hv = *(const float4*)&h1[tq + 4 * i][k];
#pragma unroll
            for (int g = 0; g < 6; ++g) acc[g][i] = dot4(w[g], hv, acc[g][i]);
          }
        }
      }
#pragma unroll
      for (int g = 0; g < 6; ++g) {
        const int row = tj + g * 64;
#pragma unroll
        for (int i = 0; i < 4; ++i) {
          if (row < 256) S[tq + 4 * i][row] += acc[g][i];
          else           S[tq + 4 * i][row + 128] = acc[g][i];
        }
      }
    }
    __syncthreads();

#pragma unroll
    for (int rep = 0; rep < (BT * HDIM) / THREADS; ++rep) {
      const int idx = tid + rep * THREADS;
      const int b = idx >> 7;
      const int d = idx & 127;
      const float r = sigmoidf(S[b][d]);
      const float z = sigmoidf(S[b][d + 128]);
      const float nn = tanhf(S[b][d + 384] + r * S[b][d + 256]);
      const float h2n = (1.0f - z) * nn + z * h2[b][d];
      h2[b][d] = h2n;
      S[b][d] = cosf(h2n) + 1e-10f;
    }
    __syncthreads();

    {
      float acc[2][4];
#pragma unroll
      for (int g = 0; g < 2; ++g) {
        const float bias = b1n[tj + g * 64];
#pragma unroll
        for (int i = 0; i < 4; ++i) acc[g][i] = bias;
      }
      for (int kk = 0; kk < HDIM; kk += 16) {
#pragma unroll
        for (int s = 0; s < 4; ++s) {
          const int k = kk + s * 4;
          float4 w[2];
          w[0] = *(const float4*)(W1n + (size_t)(tj)*HDIM + k);
          w[1] = *(const float4*)(W1n + (size_t)(tj + 64) * HDIM + k);
#pragma unroll
          for (int i = 0; i < 4; ++i) {
            const float4 sv = *(const float4*)&S[tq + 4 * i][k];
            acc[0][i] = dot4(w[0], sv, acc[0][i]);
            acc[1][i] = dot4(w[1], sv, acc[1][i]);
          }
        }
      }
#pragma unroll
      for (int g = 0; g < 2; ++g)
#pragma unroll
        for (int i = 0; i < 4; ++i)
          S[tq + 4 * i][384 + tj + g * 64] = fmaxf(acc[g][i], 0.0f);
    }
    __syncthreads();

    {
      const int ln = tid & 15;
      const int b = tid >> 4;
      const int kb = ln * 8;
      float a0 = 0.0f, a1 = 0.0f;
#pragma unroll
      for (int k = 0; k < 8; ++k) {
        const float hd = S[b][384 + kb + k];
        a0 = fmaf(W2n[kb + k], hd, a0);
        a1 = fmaf(W2n[HDIM + kb + k], hd, a1);
      }
#pragma unroll
      for (int off = 8; off >= 1; off >>= 1) {
        a0 += __shfl_xor(a0, off, 16);
        a1 += __shfl_xor(a1, off, 16);
      }
      if (ln == 0) {
        const float l0 = a0 + b2n[0];
        const float l1 = a1 + b2n[1];
        const float m = fmaxf(l0, l1);
        const float e0 = expf(l0 - m);
        const float e1 = expf(l1 - m);
        const float sum = e0 + e1;
        const float p0 = e0 / sum + 1e-10f;
        const float p1 = e1 / sum + 1e-10f;
        const int gb = b0 + b;
        out[((size_t)gb * NSTEPS + n) * 2 + 0] = p0;
        out[((size_t)gb * NSTEPS + n) * 2 + 1] = p1;

        uint32_t k0n, k1n;
        tf2x32(0u, 42u, 0u, (uint32_t)n, k0n, k1n);
        uint32_t o0, o1;
        tf2x32(k0n, k1n, 0u, (uint32_t)(2 * gb), o0, o1);
        const float u0 = u01_from_bits(o0 ^ o1);
        tf2x32(k0n, k1n, 0u, (uint32_t)(2 * gb + 1), o0, o1);
        const float u1 = u01_from_bits(o0 ^ o1);
        const float g0 = -logf(-logf(u0));
        const float g1 = -logf(-logf(u1));
        const float z0 = logf(p0) + g0;
        const float z1 = logf(p1) + g1;
        const int smp = (z1 > z0) ? 1 : 0;
        xin[b][0] = (smp == 0) ? 1.0f : 0.0f;
        xin[b][1] = (smp == 1) ? 1.0f : 0.0f;
      }
    }
    __syncthreads();
  }
}

extern "C" void kernel_launch(void* const* d_in, const int* in_sizes, int n_in,
                              void* d_out, int out_size, void* d_ws, size_t ws_size,
                              hipStream_t stream) {
  (void)in_sizes; (void)n_in; (void)out_size;
  const float* inputs = (const float*)d_in[0];
  const float* Wih0 = (const float*)d_in[1];
  const float* Whh0 = (const float*)d_in[2];
  const float* bih0 = (const float*)d_in[3];
  const float* bhh0 = (const float*)d_in[4];
  const float* Wih1 = (const float*)d_in[5];
  const float* Whh1 = (const float*)d_in[6];
  const float* bih1 = (const float*)d_in[7];
  const float* bhh1 = (const float*)d_in[8];
  const float* W1 = (const float*)d_in[9];
  const float* b1 = (const float*)d_in[10];
  const float* W2 = (const float*)d_in[11];
  const float* b2 = (const float*)d_in[12];
  float* out = (float*)d_out;

  constexpr size_t EB = 6291456;        // 128*24*4*64*8
  constexpr size_t EW1 = 2097152;       // 128*8*4*64*8
  constexpr size_t WS_NEEDED = (6 * EB + 2 * EW1) * sizeof(_Float16);

  if (ws_size >= WS_NEEDED) {
    _Float16* w = (_Float16*)d_ws;
    _Float16* Whh0_1 = w;
    _Float16* Whh0_2 = w + EB;
    _Float16* Wih1_1 = w + 2 * EB;
    _Float16* Wih1_2 = w + 3 * EB;
    _Float16* Whh1_1 = w + 4 * EB;
    _Float16* Whh1_2 = w + 5 * EB;
    _Float16* W1_1 = w + 6 * EB;
    _Float16* W1_2 = w + 6 * EB + EW1;

    hipLaunchKernelGGL(preprocess_split_kernel, dim3(3072), dim3(256), 0, stream,
                       Whh0, Whh0_1, Whh0_2, 786432, 24);
    hipLaunchKernelGGL(preprocess_split_kernel, dim3(3072), dim3(256), 0, stream,
                       Wih1, Wih1_1, Wih1_2, 786432, 24);
    hipLaunchKernelGGL(preprocess_split_kernel, dim3(3072), dim3(256), 0, stream,
                       Whh1, Whh1_1, Whh1_2, 786432, 24);
    hipLaunchKernelGGL(preprocess_split_kernel, dim3(1024), dim3(256), 0, stream,
                       W1, W1_1, W1_2, 262144, 8);
    hipLaunchKernelGGL(rnn_wavefn_mfma_kernel, dim3(8192 / BTM), dim3(THM), 0, stream,
                       inputs, Wih0, bih0, bhh0, bih1, bhh1, b1, W2, b2,
                       Whh0_1, Whh0_2, Wih1_1, Wih1_2, Whh1_1, Whh1_2, W1_1, W1_2,
                       out);
  } else {
    hipLaunchKernelGGL(rnn_wavefn_fp32_kernel, dim3(8192 / BT), dim3(THREADS), 0, stream,
                       inputs, Wih0, Whh0, bih0, bhh0, Wih1, Whh1, bih1, bhh1,
                       W1, b1, W2, b2, out);
  }
}

// Round 6
// 2346.285 us; speedup vs baseline: 6.2033x; 1.4178x over previous
//
#include <hip/hip_runtime.h>
#include <cstdint>

// binary_disordered_RNNwavefunction: 128-step 2-layer GRU + MLP + softmax +
// threefry categorical sampling, B=8192, H=128, I=2.
//
// R6 (vs R5, which measured 55% idle at 2 waves/SIMD):
//  1. GH0+GH1a merged into one GEMM phase (both read prev-step state):
//     6 jt tiles / wave -> 48 independent B-loads pipelined per phase.
//     Needs split gate buffers S0 (GRU0) / S1 (GRU1); cos-frag arrays alias
//     into S0 (disjoint live ranges). LDS ~148 KB, 1 block/CU.
//  2. Explicit double-buffered B prefetch in all GEMM phases.
//  3. Combine ownership by d-octet (b=tid&31, d in [8*(tid>>5),+8)):
//     A-frag scatter writes become ds_write_b128 at wave-consecutive
//     addresses (R5's 1.38e8 bank conflicts came from b16 scatters).
//
// Numerics (verified R4/R5, absmax 0.0039 = comparison floor): split-f16
// a = a1 + a2s/4096; 3 MFMAs/tile; dropped A2sB2s ~3e-8.
// RNG (verified): modern JAX threefry_partitionable semantics.
// R2 lesson: few blocks, lockstep L2 reuse. R5 lesson: AI per B-load ~ BTM.

namespace {

constexpr int NSTEPS = 128;
constexpr int HDIM = 128;
constexpr int G3H = 384;

constexpr int BTM = 32;        // batch rows per block
constexpr int THM = 512;       // threads (8 waves)
constexpr int S0P = 385;       // S0 stride (==1 mod 32)
constexpr int S1P = 513;       // S1 stride (==1 mod 32)

// fallback (R3) config
constexpr int BT = 16;
constexpr int THREADS = 256;
constexpr int HP = 132;
constexpr int SP = 516;

typedef _Float16 half8 __attribute__((ext_vector_type(8)));
typedef float f32x4 __attribute__((ext_vector_type(4)));

constexpr float LO_SCALE = 4096.0f;
constexpr float LO_INV = 2.44140625e-4f;   // 1/4096
constexpr float F16_MIN_NORM = 6.104e-5f;

__device__ __forceinline__ void split_f16(float x, _Float16& a1, _Float16& a2s) {
  _Float16 h = (fabsf(x) < F16_MIN_NORM) ? (_Float16)0.0f : (_Float16)x;
  a1 = h;
  a2s = (_Float16)((x - (float)h) * LO_SCALE);
}

__device__ __forceinline__ void tf2x32(uint32_t k0, uint32_t k1,
                                       uint32_t x0, uint32_t x1,
                                       uint32_t& o0, uint32_t& o1) {
  const uint32_t ks2 = k0 ^ k1 ^ 0x1BD11BDAu;
  uint32_t v0 = x0 + k0;
  uint32_t v1 = x1 + k1;
  const uint32_t ks[3] = {k0, k1, ks2};
  const uint32_t rotA[4] = {13u, 15u, 26u, 6u};
  const uint32_t rotB[4] = {17u, 29u, 16u, 24u};
#pragma unroll
  for (int i = 0; i < 5; ++i) {
#pragma unroll
    for (int j = 0; j < 4; ++j) {
      const uint32_t r = (i & 1) ? rotB[j] : rotA[j];
      v0 += v1;
      v1 = (v1 << r) | (v1 >> (32u - r));
      v1 ^= v0;
    }
    v0 += ks[(i + 1) % 3];
    v1 += ks[(i + 2) % 3] + (uint32_t)(i + 1);
  }
  o0 = v0;
  o1 = v1;
}

__device__ __forceinline__ float u01_from_bits(uint32_t bits) {
  const float tiny = 1.1754943508222875e-38f;
  float f = __uint_as_float((bits >> 9) | 0x3F800000u) - 1.0f;
  float u = f * (1.0f - tiny) + tiny;
  return fmaxf(tiny, u);
}

__device__ __forceinline__ float sigmoidf(float x) {
  return 1.0f / (1.0f + expf(-x));
}

__device__ __forceinline__ float dot4(const float4 a, const float4 b, float c) {
  c = fmaf(a.x, b.x, c);
  c = fmaf(a.y, b.y, c);
  c = fmaf(a.z, b.z, c);
  c = fmaf(a.w, b.w, c);
  return c;
}

__device__ __forceinline__ void load_Afrag(const _Float16* arr, int lane,
                                           half8 (&A)[2][4]) {
#pragma unroll
  for (int mt = 0; mt < 2; ++mt)
#pragma unroll
    for (int kt = 0; kt < 4; ++kt)
      A[mt][kt] = *(const half8*)(arr + mt * 2048 + (kt * 64 + lane) * 8);
}

__device__ __forceinline__ void load_B(const _Float16* __restrict__ B1,
                                       const _Float16* __restrict__ B2,
                                       int jt, int lane,
                                       half8 (&b1)[4], half8 (&b2)[4]) {
#pragma unroll
  for (int kt = 0; kt < 4; ++kt) {
    const size_t o = ((size_t)(jt * 4 + kt) * 64 + lane) * 8;
    b1[kt] = *(const half8*)(B1 + o);
    b2[kt] = *(const half8*)(B2 + o);
  }
}

__device__ __forceinline__ void mfma_regs(const half8 (&A1)[2][4],
                                          const half8 (&A2)[2][4],
                                          const half8 (&b1)[4],
                                          const half8 (&b2)[4],
                                          f32x4 (&c1)[2], f32x4 (&c2)[2]) {
#pragma unroll
  for (int kt = 0; kt < 4; ++kt)
#pragma unroll
    for (int mt = 0; mt < 2; ++mt) {
      c1[mt] = __builtin_amdgcn_mfma_f32_16x16x32_f16(A1[mt][kt], b1[kt], c1[mt], 0, 0, 0);
      c2[mt] = __builtin_amdgcn_mfma_f32_16x16x32_f16(A1[mt][kt], b2[kt], c2[mt], 0, 0, 0);
      c2[mt] = __builtin_amdgcn_mfma_f32_16x16x32_f16(A2[mt][kt], b1[kt], c2[mt], 0, 0, 0);
    }
}

}  // namespace

// ---------------------------------------------------------------------------
// Preprocess: fp32 W[n][JT*16][128] -> frag-layout split-f16 arrays (as R4)
// ---------------------------------------------------------------------------
extern "C" __global__ __launch_bounds__(256)
void preprocess_split_kernel(const float* __restrict__ src,
                             _Float16* __restrict__ d1,
                             _Float16* __restrict__ d2,
                             int total, int JT) {
  const int idx = blockIdx.x * 256 + threadIdx.x;
  if (idx >= total) return;
  const int lane = idx & 63;
  const int kt = (idx >> 6) & 3;
  const int rest = idx >> 8;
  const int jt = rest % JT;
  const int nstep = rest / JT;

  const int j = jt * 16 + (lane & 15);
  const int k0 = kt * 32 + ((lane >> 4) << 3);
  const float* p = src + ((size_t)nstep * (JT * 16) + j) * 128 + k0;
  const float4 w0 = *(const float4*)p;
  const float4 w1 = *(const float4*)(p + 4);
  const float xs[8] = {w0.x, w0.y, w0.z, w0.w, w1.x, w1.y, w1.z, w1.w};

  half8 o1, o2;
#pragma unroll
  for (int t = 0; t < 8; ++t) {
    _Float16 a1, a2s;
    split_f16(xs[t], a1, a2s);
    o1[t] = a1;
    o2[t] = a2s;
  }
  *(half8*)(d1 + (size_t)idx * 8) = o1;
  *(half8*)(d2 + (size_t)idx * 8) = o2;
}

// ---------------------------------------------------------------------------
// Main MFMA kernel: BT=32, 512 threads, 1 block/CU
// ---------------------------------------------------------------------------
extern "C" __global__ __launch_bounds__(512, 2)
void rnn_wavefn_mfma_kernel(const float* __restrict__ inputs,
                            const float* __restrict__ Wih0,
                            const float* __restrict__ bih0,
                            const float* __restrict__ bhh0,
                            const float* __restrict__ bih1,
                            const float* __restrict__ bhh1,
                            const float* __restrict__ b1,
                            const float* __restrict__ W2,
                            const float* __restrict__ b2,
                            const _Float16* __restrict__ Whh0_1,
                            const _Float16* __restrict__ Whh0_2,
                            const _Float16* __restrict__ Wih1_1,
                            const _Float16* __restrict__ Wih1_2,
                            const _Float16* __restrict__ Whh1_1,
                            const _Float16* __restrict__ Whh1_2,
                            const _Float16* __restrict__ W1_1,
                            const _Float16* __restrict__ W1_2,
                            float* __restrict__ out) {
  // S0: GRU0 gates (cols 0..383). cos-frag arrays alias its first 16 KB
  // (live ranges disjoint: S0 live GEMM->C0; cs live C1->HDN).
  __shared__ __align__(16) float S0[BTM][S0P];   // 49,280 B
  __shared__ float S1[BTM][S1P];                 // 65,664 B  r,z|gh_n|gi_n/hdn
  __shared__ _Float16 h1A1[4096], h1A2[4096];    // A-frag split layouts
  __shared__ _Float16 h2A1[4096], h2A2[4096];    // 4 x 8 KB = 32,768 B
  __shared__ float xin[BTM][2];

  _Float16* const csA1 = (_Float16*)&S0[0][0];
  _Float16* const csA2 = csA1 + 4096;

  const int tid = threadIdx.x;
  const int b0 = blockIdx.x * BTM;
  const int wv = tid >> 6;        // 0..7
  const int lane = tid & 63;
  const int lm = lane & 15;
  const int m0 = (lane >> 4) * 4;

  // combine ownership: b = tid&31, d in [8*(tid>>5), +8)
  const int cb = tid & 31;
  const int ct5 = tid >> 5;       // 0..15
  const int d0 = ct5 * 8;
  // A-frag base for this thread's (cb, d-octet): contiguous half8
  const int ibase = ((cb >> 4) * 2048 +
                     (((ct5 >> 2) << 6) + ((ct5 & 3) << 4) + (cb & 15)) * 8);

  float h1r[8], h2r[8];
#pragma unroll
  for (int i = 0; i < 8; ++i) { h1r[i] = 0.0f; h2r[i] = 0.0f; }
  for (int i = tid; i < 4096; i += THM) {
    h1A1[i] = (_Float16)0.0f; h1A2[i] = (_Float16)0.0f;
    h2A1[i] = (_Float16)0.0f; h2A2[i] = (_Float16)0.0f;
  }
  if (tid < BTM * 2) {
    xin[tid >> 1][tid & 1] = inputs[(b0 + (tid >> 1)) * 2 + (tid & 1)];
  }
  __syncthreads();

  for (int n = 0; n < NSTEPS; ++n) {
    const float* __restrict__ Wih0n = Wih0 + (size_t)n * G3H * 2;
    const float* __restrict__ bih0n = bih0 + (size_t)n * G3H;
    const float* __restrict__ bhh0n = bhh0 + (size_t)n * G3H;
    const float* __restrict__ bih1n = bih1 + (size_t)n * G3H;
    const float* __restrict__ bhh1n = bhh1 + (size_t)n * G3H;
    const float* __restrict__ b1n = b1 + (size_t)n * HDIM;
    const float* __restrict__ W2n = W2 + (size_t)n * 2 * HDIM;
    const float* __restrict__ b2n = b2 + (size_t)n * 2;
    const size_t fo3 = (size_t)n * 49152;
    const size_t fo1 = (size_t)n * 16384;

    // ---------- merged GEMM: GH0 (h1 x Whh0 -> S0) + GH1a (h2 x Whh1 -> S1)
    // Both read only prev-step state; 6 jt jobs/wave, B double-buffered.
    {
      half8 A1[2][4], A2[2][4];
      load_Afrag(h1A1, lane, A1);
      load_Afrag(h1A2, lane, A2);
      half8 Bb1[2][4], Bb2[2][4];
      load_B(Whh0_1 + fo3, Whh0_2 + fo3, wv * 3, lane, Bb1[0], Bb2[0]);
#pragma unroll
      for (int t = 0; t < 6; ++t) {
        const int cur = t & 1;
        if (t < 5) {
          const int tn = t + 1;
          const _Float16* nB1 = (tn < 3) ? (Whh0_1 + fo3) : (Whh1_1 + fo3);
          const _Float16* nB2 = (tn < 3) ? (Whh0_2 + fo3) : (Whh1_2 + fo3);
          load_B(nB1, nB2, wv * 3 + (tn % 3), lane, Bb1[cur ^ 1], Bb2[cur ^ 1]);
        }
        if (t == 3) {   // switch A to h2 for GH1a jobs
          load_Afrag(h2A1, lane, A1);
          load_Afrag(h2A2, lane, A2);
        }
        const int jt = wv * 3 + (t % 3);
        f32x4 c1[2] = {{0.f,0.f,0.f,0.f},{0.f,0.f,0.f,0.f}};
        f32x4 c2[2] = {{0.f,0.f,0.f,0.f},{0.f,0.f,0.f,0.f}};
        mfma_regs(A1, A2, Bb1[cur], Bb2[cur], c1, c2);
        const int col = jt * 16 + lm;
        if (t < 3) {
          const float bias = bhh0n[col];
#pragma unroll
          for (int mt = 0; mt < 2; ++mt)
#pragma unroll
            for (int r = 0; r < 4; ++r)
              S0[mt * 16 + m0 + r][col] = bias + fmaf(c2[mt][r], LO_INV, c1[mt][r]);
        } else {
          const float bias = bhh1n[col];
#pragma unroll
          for (int mt = 0; mt < 2; ++mt)
#pragma unroll
            for (int r = 0; r < 4; ++r)
              S1[mt * 16 + m0 + r][col] = bias + fmaf(c2[mt][r], LO_INV, c1[mt][r]);
        }
      }
    }
    __syncthreads();

    // ---------- C0: GRU0 combine -> h1 regs + one b128 A-frag write per array
    {
      const float x0 = xin[cb][0];
      const float x1 = xin[cb][1];
      float wr[16], wz[16], wn[16], br[8], bz[8], bn[8];
#pragma unroll
      for (int q = 0; q < 4; ++q) {
        *(float4*)&wr[q * 4] = *(const float4*)(Wih0n + d0 * 2 + q * 4);
        *(float4*)&wz[q * 4] = *(const float4*)(Wih0n + (d0 + 128) * 2 + q * 4);
        *(float4*)&wn[q * 4] = *(const float4*)(Wih0n + (d0 + 256) * 2 + q * 4);
      }
      *(float4*)&br[0] = *(const float4*)(bih0n + d0);
      *(float4*)&br[4] = *(const float4*)(bih0n + d0 + 4);
      *(float4*)&bz[0] = *(const float4*)(bih0n + 128 + d0);
      *(float4*)&bz[4] = *(const float4*)(bih0n + 128 + d0 + 4);
      *(float4*)&bn[0] = *(const float4*)(bih0n + 256 + d0);
      *(float4*)&bn[4] = *(const float4*)(bih0n + 256 + d0 + 4);
      half8 o1, o2;
#pragma unroll
      for (int j = 0; j < 8; ++j) {
        const int d = d0 + j;
        const float gir = fmaf(wr[2 * j], x0, fmaf(wr[2 * j + 1], x1, br[j]));
        const float giz = fmaf(wz[2 * j], x0, fmaf(wz[2 * j + 1], x1, bz[j]));
        const float gin = fmaf(wn[2 * j], x0, fmaf(wn[2 * j + 1], x1, bn[j]));
        const float r = sigmoidf(gir + S0[cb][d]);
        const float z = sigmoidf(giz + S0[cb][d + 128]);
        const float nn = tanhf(gin + r * S0[cb][d + 256]);
        const float h1n = (1.0f - z) * nn + z * h1r[j];
        h1r[j] = h1n;
        _Float16 a1, a2s;
        split_f16(h1n, a1, a2s);
        o1[j] = a1;
        o2[j] = a2s;
      }
      *(half8*)(h1A1 + ibase) = o1;
      *(half8*)(h1A2 + ibase) = o2;
    }
    __syncthreads();

    // ---------- GH1b: gi1 = bih1 + Wih1 . h1new; r,z += into S1; gi_n separate
    {
      half8 A1[2][4], A2[2][4];
      load_Afrag(h1A1, lane, A1);
      load_Afrag(h1A2, lane, A2);
      half8 Bb1[2][4], Bb2[2][4];
      load_B(Wih1_1 + fo3, Wih1_2 + fo3, wv * 3, lane, Bb1[0], Bb2[0]);
#pragma unroll
      for (int t = 0; t < 3; ++t) {
        const int cur = t & 1;
        if (t < 2)
          load_B(Wih1_1 + fo3, Wih1_2 + fo3, wv * 3 + t + 1, lane,
                 Bb1[cur ^ 1], Bb2[cur ^ 1]);
        const int jt = wv * 3 + t;
        f32x4 c1[2] = {{0.f,0.f,0.f,0.f},{0.f,0.f,0.f,0.f}};
        f32x4 c2[2] = {{0.f,0.f,0.f,0.f},{0.f,0.f,0.f,0.f}};
        mfma_regs(A1, A2, Bb1[cur], Bb2[cur], c1, c2);
        const int col = jt * 16 + lm;
        const float bias = bih1n[col];
        if (jt < 16) {   // r,z: accumulate gi+gh (same-thread slots as GH1a)
#pragma unroll
          for (int mt = 0; mt < 2; ++mt)
#pragma unroll
            for (int r = 0; r < 4; ++r)
              S1[mt * 16 + m0 + r][col] += bias + fmaf(c2[mt][r], LO_INV, c1[mt][r]);
        } else {         // gi_n at col+128 (cols 384..511)
#pragma unroll
          for (int mt = 0; mt < 2; ++mt)
#pragma unroll
            for (int r = 0; r < 4; ++r)
              S1[mt * 16 + m0 + r][col + 128] = bias + fmaf(c2[mt][r], LO_INV, c1[mt][r]);
        }
      }
    }
    __syncthreads();

    // ---------- C1: GRU1 combine -> h2 regs; h2/cos frag b128 writes
    {
      half8 o1, o2, p1, p2;
#pragma unroll
      for (int j = 0; j < 8; ++j) {
        const int d = d0 + j;
        const float r = sigmoidf(S1[cb][d]);
        const float z = sigmoidf(S1[cb][d + 128]);
        const float nn = tanhf(S1[cb][d + 384] + r * S1[cb][d + 256]);
        const float h2n = (1.0f - z) * nn + z * h2r[j];
        h2r[j] = h2n;
        _Float16 a1, a2s;
        split_f16(h2n, a1, a2s);
        o1[j] = a1;
        o2[j] = a2s;
        const float cv = cosf(h2n) + 1e-10f;
        split_f16(cv, a1, a2s);
        p1[j] = a1;
        p2[j] = a2s;
      }
      *(half8*)(h2A1 + ibase) = o1;
      *(half8*)(h2A2 + ibase) = o2;
      *(half8*)(csA1 + ibase) = p1;
      *(half8*)(csA2 + ibase) = p2;
    }
    __syncthreads();

    // ---------- HDN: S1[b][384+d] = relu(b1[d] + W1[d,:].cos[b,:])
    {
      half8 A1[2][4], A2[2][4];
      load_Afrag(csA1, lane, A1);
      load_Afrag(csA2, lane, A2);
      half8 b1v[4], b2v[4];
      load_B(W1_1 + fo1, W1_2 + fo1, wv, lane, b1v, b2v);
      f32x4 c1[2] = {{0.f,0.f,0.f,0.f},{0.f,0.f,0.f,0.f}};
      f32x4 c2[2] = {{0.f,0.f,0.f,0.f},{0.f,0.f,0.f,0.f}};
      mfma_regs(A1, A2, b1v, b2v, c1, c2);
      const int col = wv * 16 + lm;
      const float bias = b1n[col];
#pragma unroll
      for (int mt = 0; mt < 2; ++mt)
#pragma unroll
        for (int r = 0; r < 4; ++r)
          S1[mt * 16 + m0 + r][384 + col] =
              fmaxf(bias + fmaf(c2[mt][r], LO_INV, c1[mt][r]), 0.0f);
    }
    __syncthreads();

    // ---------- OUT: logits, softmax+1e-10, store p, threefry-gumbel sample
    {
      const int ln = tid & 15;
      const int ob = tid >> 4;    // 0..31
      const int kb = ln * 8;
      float a0 = 0.0f, a1 = 0.0f;
#pragma unroll
      for (int k = 0; k < 8; ++k) {
        const float hd = S1[ob][384 + kb + k];
        a0 = fmaf(W2n[kb + k], hd, a0);
        a1 = fmaf(W2n[HDIM + kb + k], hd, a1);
      }
#pragma unroll
      for (int off = 8; off >= 1; off >>= 1) {
        a0 += __shfl_xor(a0, off, 16);
        a1 += __shfl_xor(a1, off, 16);
      }
      if (ln == 0) {
        const float l0 = a0 + b2n[0];
        const float l1 = a1 + b2n[1];
        const float m = fmaxf(l0, l1);
        const float e0 = expf(l0 - m);
        const float e1 = expf(l1 - m);
        const float sum = e0 + e1;
        const float p0 = e0 / sum + 1e-10f;
        const float p1 = e1 / sum + 1e-10f;
        const int gb = b0 + ob;
        out[((size_t)gb * NSTEPS + n) * 2 + 0] = p0;
        out[((size_t)gb * NSTEPS + n) * 2 + 1] = p1;

        uint32_t k0n, k1n;
        tf2x32(0u, 42u, 0u, (uint32_t)n, k0n, k1n);
        uint32_t o0, o1;
        tf2x32(k0n, k1n, 0u, (uint32_t)(2 * gb), o0, o1);
        const float u0 = u01_from_bits(o0 ^ o1);
        tf2x32(k0n, k1n, 0u, (uint32_t)(2 * gb + 1), o0, o1);
        const float u1 = u01_from_bits(o0 ^ o1);
        const float g0 = -logf(-logf(u0));
        const float g1 = -logf(-logf(u1));
        const float z0 = logf(p0) + g0;
        const float z1 = logf(p1) + g1;
        const int smp = (z1 > z0) ? 1 : 0;
        xin[ob][0] = (smp == 0) ? 1.0f : 0.0f;
        xin[ob][1] = (smp == 1) ? 1.0f : 0.0f;
      }
    }
    __syncthreads();
  }
}

// ---------------------------------------------------------------------------
// Fallback: R3 fp32-VALU kernel (proven, 7.2 ms) — used if ws too small.
// ---------------------------------------------------------------------------
extern "C" __global__ __launch_bounds__(256, 2)
void rnn_wavefn_fp32_kernel(const float* __restrict__ inputs,
                            const float* __restrict__ Wih0,
                            const float* __restrict__ Whh0,
                            const float* __restrict__ bih0,
                            const float* __restrict__ bhh0,
                            const float* __restrict__ Wih1,
                            const float* __restrict__ Whh1,
                            const float* __restrict__ bih1,
                            const float* __restrict__ bhh1,
                            const float* __restrict__ W1,
                            const float* __restrict__ b1,
                            const float* __restrict__ W2,
                            const float* __restrict__ b2,
                            float* __restrict__ out) {
  __shared__ float h1[BT][HP];
  __shared__ float h2[BT][HP];
  __shared__ float S[BT][SP];
  __shared__ float xin[BT][2];

  const int tid = threadIdx.x;
  const int b0 = blockIdx.x * BT;
  const int tj = tid >> 2;
  const int tq = tid & 3;

  for (int i = tid; i < BT * HP; i += THREADS) {
    ((float*)h1)[i] = 0.0f;
    ((float*)h2)[i] = 0.0f;
  }
  if (tid < BT * 2) {
    xin[tid >> 1][tid & 1] = inputs[(b0 + (tid >> 1)) * 2 + (tid & 1)];
  }
  __syncthreads();

  for (int n = 0; n < NSTEPS; ++n) {
    const float* __restrict__ Wih0n = Wih0 + (size_t)n * G3H * 2;
    const float* __restrict__ Whh0n = Whh0 + (size_t)n * G3H * HDIM;
    const float* __restrict__ bih0n = bih0 + (size_t)n * G3H;
    const float* __restrict__ bhh0n = bhh0 + (size_t)n * G3H;
    const float* __restrict__ Wih1n = Wih1 + (size_t)n * G3H * HDIM;
    const float* __restrict__ Whh1n = Whh1 + (size_t)n * G3H * HDIM;
    const float* __restrict__ bih1n = bih1 + (size_t)n * G3H;
    const float* __restrict__ bhh1n = bhh1 + (size_t)n * G3H;
    const float* __restrict__ W1n = W1 + (size_t)n * HDIM * HDIM;
    const float* __restrict__ b1n = b1 + (size_t)n * HDIM;
    const float* __restrict__ W2n = W2 + (size_t)n * 2 * HDIM;
    const float* __restrict__ b2n = b2 + (size_t)n * 2;

    {
      float acc[6][4];
#pragma unroll
      for (int g = 0; g < 6; ++g) {
        const float bias = bhh0n[tj + g * 64];
#pragma unroll
        for (int i = 0; i < 4; ++i) acc[g][i] = bias;
      }
      for (int kk = 0; kk < HDIM; kk += 16) {
#pragma unroll
        for (int s = 0; s < 4; ++s) {
          const int k = kk + s * 4;
          float4 w[6];
#pragma unroll
          for (int g = 0; g < 6; ++g)
            w[g] = *(const float4*)(Whh0n + (size_t)(tj + g * 64) * HDIM + k);
#pragma unroll
          for (int i = 0; i < 4; ++i) {
            const float4 hv = *(const float4*)&h1[tq + 4 * i][k];
#pragma unroll
            for (int g = 0; g < 6; ++g) acc[g][i] = dot4(w[g], hv, acc[g][i]);
          }
        }
      }
#pragma unroll
      for (int g = 0; g < 6; ++g)
#pragma unroll
        for (int i = 0; i < 4; ++i) S[tq + 4 * i][tj + g * 64] = acc[g][i];
    }
    __syncthreads();

#pragma unroll
    for (int rep = 0; rep < (BT * HDIM) / THREADS; ++rep) {
      const int idx = tid + rep * THREADS;
      const int b = idx >> 7;
      const int d = idx & 127;
      const float x0 = xin[b][0];
      const float x1 = xin[b][1];
      const float gir = fmaf(Wih0n[d * 2 + 0], x0, fmaf(Wih0n[d * 2 + 1], x1, bih0n[d]));
      const float giz = fmaf(Wih0n[(d + 128) * 2 + 0], x0,
                             fmaf(Wih0n[(d + 128) * 2 + 1], x1, bih0n[d + 128]));
      const float gin = fmaf(Wih0n[(d + 256) * 2 + 0], x0,
                             fmaf(Wih0n[(d + 256) * 2 + 1], x1, bih0n[d + 256]));
      const float r = sigmoidf(gir + S[b][d]);
      const float z = sigmoidf(giz + S[b][d + 128]);
      const float nn = tanhf(gin + r * S[b][d + 256]);
      h1[b][d] = (1.0f - z) * nn + z * h1[b][d];
    }
    __syncthreads();

    {
      float acc[6][4];
#pragma unroll
      for (int g = 0; g < 6; ++g) {
        const float bias = bhh1n[tj + g * 64];
#pragma unroll
        for (int i = 0; i < 4; ++i) acc[g][i] = bias;
      }
      for (int kk = 0; kk < HDIM; kk += 16) {
#pragma unroll
        for (int s = 0; s < 4; ++s) {
          const int k = kk + s * 4;
          float4 w[6];
#pragma unroll
          for (int g = 0; g < 6; ++g)
            w[g] = *(const float4*)(Whh1n + (size_t)(tj + g * 64) * HDIM + k);
#pragma unroll
          for (int i = 0; i < 4; ++i) {
            const float4 hv = *(const float4*)&h2[tq + 4 * i][k];
#pragma unroll
            for (int g = 0; g < 6; ++g) acc[g][i] = dot4(w[g], hv, acc[g][i]);
          }
        }
      }
#pragma unroll
      for (int g = 0; g < 6; ++g)
#pragma unroll
        for (int i = 0; i < 4; ++i) S[tq + 4 * i][tj + g * 64] = acc[g][i];
    }

    {
      float acc[6][4];
#pragma unroll
      for (int g = 0; g < 6; ++g) {
        const float bias = bih1n[tj + g * 64];
#pragma unroll
        for (int i = 0; i < 4; ++i) acc[g][i] = bias;
      }
      for (int kk = 0; kk < HDIM; kk += 16) {
#pragma unroll
        for (int s = 0; s < 4; ++s) {
          const int k = kk + s * 4;
          float4 w[6];
#pragma unroll
          for (int g = 0; g < 6; ++g)
            w[g] = *(const float4*)(Wih1n + (size_t)(tj + g * 64) * HDIM + k);
#pragma unroll
          for (int i = 0; i < 4; ++i) {
            const float4 hv = *(const float4*)&h1[tq + 4 * i][k];
#pragma unroll
            for (int g = 0; g < 6; ++g) acc[g][i] = dot4(w[g], hv, acc[g][i]);
          }
        }
      }
#pragma unroll
      for (int g = 0; g < 6; ++g) {
        const int row = tj + g * 64;
#pragma unroll
        for (int i = 0; i < 4; ++i) {
          if (row < 256) S[tq + 4 * i][row] += acc[g][i];
          else           S[tq + 4 * i][row + 128] = acc[g][i];
        }
      }
    }
    __syncthreads();

#pragma unroll
    for (int rep = 0; rep < (BT * HDIM) / THREADS; ++rep) {
      const int idx = tid + rep * THREADS;
      const int b = idx >> 7;
      const int d = idx & 127;
      const float r = sigmoidf(S[b][d]);
      const float z = sigmoidf(S[b][d + 128]);
      const float nn = tanhf(S[b][d + 384] + r * S[b][d + 256]);
      const float h2n = (1.0f - z) * nn + z * h2[b][d];
      h2[b][d] = h2n;
      S[b][d] = cosf(h2n) + 1e-10f;
    }
    __syncthreads();

    {
      float acc[2][4];
#pragma unroll
      for (int g = 0; g < 2; ++g) {
        const float bias = b1n[tj + g * 64];
#pragma unroll
        for (int i = 0; i < 4; ++i) acc[g][i] = bias;
      }
      for (int kk = 0; kk < HDIM; kk += 16) {
#pragma unroll
        for (int s = 0; s < 4; ++s) {
          const int k = kk + s * 4;
          float4 w[2];
          w[0] = *(const float4*)(W1n + (size_t)(tj)*HDIM + k);
          w[1] = *(const float4*)(W1n + (size_t)(tj + 64) * HDIM + k);
#pragma unroll
          for (int i = 0; i < 4; ++i) {
            const float4 sv = *(const float4*)&S[tq + 4 * i][k];
            acc[0][i] = dot4(w[0], sv, acc[0][i]);
            acc[1][i] = dot4(w[1], sv, acc[1][i]);
          }
        }
      }
#pragma unroll
      for (int g = 0; g < 2; ++g)
#pragma unroll
        for (int i = 0; i < 4; ++i)
          S[tq + 4 * i][384 + tj + g * 64] = fmaxf(acc[g][i], 0.0f);
    }
    __syncthreads();

    {
      const int ln = tid & 15;
      const int b = tid >> 4;
      const int kb = ln * 8;
      float a0 = 0.0f, a1 = 0.0f;
#pragma unroll
      for (int k = 0; k < 8; ++k) {
        const float hd = S[b][384 + kb + k];
        a0 = fmaf(W2n[kb + k], hd, a0);
        a1 = fmaf(W2n[HDIM + kb + k], hd, a1);
      }
#pragma unroll
      for (int off = 8; off >= 1; off >>= 1) {
        a0 += __shfl_xor(a0, off, 16);
        a1 += __shfl_xor(a1, off, 16);
      }
      if (ln == 0) {
        const float l0 = a0 + b2n[0];
        const float l1 = a1 + b2n[1];
        const float m = fmaxf(l0, l1);
        const float e0 = expf(l0 - m);
        const float e1 = expf(l1 - m);
        const float sum = e0 + e1;
        const float p0 = e0 / sum + 1e-10f;
        const float p1 = e1 / sum + 1e-10f;
        const int gb = b0 + b;
        out[((size_t)gb * NSTEPS + n) * 2 + 0] = p0;
        out[((size_t)gb * NSTEPS + n) * 2 + 1] = p1;

        uint32_t k0n, k1n;
        tf2x32(0u, 42u, 0u, (uint32_t)n, k0n, k1n);
        uint32_t o0, o1;
        tf2x32(k0n, k1n, 0u, (uint32_t)(2 * gb), o0, o1);
        const float u0 = u01_from_bits(o0 ^ o1);
        tf2x32(k0n, k1n, 0u, (uint32_t)(2 * gb + 1), o0, o1);
        const float u1 = u01_from_bits(o0 ^ o1);
        const float g0 = -logf(-logf(u0));
        const float g1 = -logf(-logf(u1));
        const float z0 = logf(p0) + g0;
        const float z1 = logf(p1) + g1;
        const int smp = (z1 > z0) ? 1 : 0;
        xin[b][0] = (smp == 0) ? 1.0f : 0.0f;
        xin[b][1] = (smp == 1) ? 1.0f : 0.0f;
      }
    }
    __syncthreads();
  }
}

extern "C" void kernel_launch(void* const* d_in, const int* in_sizes, int n_in,
                              void* d_out, int out_size, void* d_ws, size_t ws_size,
                              hipStream_t stream) {
  (void)in_sizes; (void)n_in; (void)out_size;
  const float* inputs = (const float*)d_in[0];
  const float* Wih0 = (const float*)d_in[1];
  const float* Whh0 = (const float*)d_in[2];
  const float* bih0 = (const float*)d_in[3];
  const float* bhh0 = (const float*)d_in[4];
  const float* Wih1 = (const float*)d_in[5];
  const float* Whh1 = (const float*)d_in[6];
  const float* bih1 = (const float*)d_in[7];
  const float* bhh1 = (const float*)d_in[8];
  const float* W1 = (const float*)d_in[9];
  const float* b1 = (const float*)d_in[10];
  const float* W2 = (const float*)d_in[11];
  const float* b2 = (const float*)d_in[12];
  float* out = (float*)d_out;

  constexpr size_t EB = 6291456;        // 128*24*4*64*8
  constexpr size_t EW1 = 2097152;       // 128*8*4*64*8
  constexpr size_t WS_NEEDED = (6 * EB + 2 * EW1) * sizeof(_Float16);

  if (ws_size >= WS_NEEDED) {
    _Float16* w = (_Float16*)d_ws;
    _Float16* Whh0_1 = w;
    _Float16* Whh0_2 = w + EB;
    _Float16* Wih1_1 = w + 2 * EB;
    _Float16* Wih1_2 = w + 3 * EB;
    _Float16* Whh1_1 = w + 4 * EB;
    _Float16* Whh1_2 = w + 5 * EB;
    _Float16* W1_1 = w + 6 * EB;
    _Float16* W1_2 = w + 6 * EB + EW1;

    hipLaunchKernelGGL(preprocess_split_kernel, dim3(3072), dim3(256), 0, stream,
                       Whh0, Whh0_1, Whh0_2, 786432, 24);
    hipLaunchKernelGGL(preprocess_split_kernel, dim3(3072), dim3(256), 0, stream,
                       Wih1, Wih1_1, Wih1_2, 786432, 24);
    hipLaunchKernelGGL(preprocess_split_kernel, dim3(3072), dim3(256), 0, stream,
                       Whh1, Whh1_1, Whh1_2, 786432, 24);
    hipLaunchKernelGGL(preprocess_split_kernel, dim3(1024), dim3(256), 0, stream,
                       W1, W1_1, W1_2, 262144, 8);
    hipLaunchKernelGGL(rnn_wavefn_mfma_kernel, dim3(8192 / BTM), dim3(THM), 0, stream,
                       inputs, Wih0, bih0, bhh0, bih1, bhh1, b1, W2, b2,
                       Whh0_1, Whh0_2, Wih1_1, Wih1_2, Whh1_1, Whh1_2, W1_1, W1_2,
                       out);
  } else {
    hipLaunchKernelGGL(rnn_wavefn_fp32_kernel, dim3(8192 / BT), dim3(THREADS), 0, stream,
                       inputs, Wih0, Whh0, bih0, bhh0, Wih1, Whh1, bih1, bhh1,
                       W1, b1, W2, b2, out);
  }
}